// Round 1
// baseline (2513.171 us; speedup 1.0000x reference)
//
#include <hip/hip_runtime.h>
#include <stdint.h>

// Problem constants: B=2, T=2048, C=2048, H=16, D=128
#define TSEQ 2048

typedef __bf16 bf16x8 __attribute__((ext_vector_type(8)));
typedef float f32x4 __attribute__((ext_vector_type(4)));

typedef const __attribute__((address_space(1))) unsigned int* gas_u32;
typedef __attribute__((address_space(3))) unsigned int* las_u32;

__device__ __forceinline__ f32x4 mfma16(bf16x8 a, bf16x8 b, f32x4 c) {
  return __builtin_amdgcn_mfma_f32_16x16x32_bf16(a, b, c, 0, 0, 0);
}

// fp32 -> bf16 round-to-nearest-even (values are finite; no NaN path needed)
__device__ __forceinline__ unsigned short f2b(float f) {
  unsigned int u = __float_as_uint(f);
  u += 0x7fffu + ((u >> 16) & 1u);
  return (unsigned short)(u >> 16);
}

// async global->LDS, 16B per lane. LDS dest must be wave-uniform base + lane*16.
__device__ __forceinline__ void gload_lds16(const unsigned short* g, unsigned short* l) {
  __builtin_amdgcn_global_load_lds((gas_u32)(const void*)g, (las_u32)(void*)l, 16, 0, 0);
}

// ---------------- cast fp32 -> bf16 (vectorized, exact-size grid) ----------------
__global__ __launch_bounds__(256) void cast_bf16_kernel(const float* __restrict__ src,
                                                        unsigned short* __restrict__ dst) {
  size_t i = ((size_t)blockIdx.x * 256 + threadIdx.x) * 4;
  float4 v = *(const float4*)(src + i);
  ushort4 o;
  o.x = f2b(v.x); o.y = f2b(v.y); o.z = f2b(v.z); o.w = f2b(v.w);
  *(ushort4*)(dst + i) = o;
}

// ---------------- cast + transpose: src (R x Cc) fp32 -> dst (Cc x R) bf16 ----------------
__global__ __launch_bounds__(256) void transpose_cast_kernel(const float* __restrict__ src,
                                                             unsigned short* __restrict__ dst,
                                                             int R, int Cc) {
  __shared__ float tile[64][65];
  int cb = blockIdx.x * 64;
  int rb = blockIdx.y * 64;
  int t = threadIdx.x;
  int tr = t >> 4;          // 0..15
  int tc = (t & 15) * 4;    // 0..60
#pragma unroll
  for (int i = 0; i < 4; i++) {
    int r = tr + 16 * i;
    float4 v = *(const float4*)(src + (size_t)(rb + r) * Cc + cb + tc);
    tile[r][tc + 0] = v.x; tile[r][tc + 1] = v.y;
    tile[r][tc + 2] = v.z; tile[r][tc + 3] = v.w;
  }
  __syncthreads();
#pragma unroll
  for (int i = 0; i < 4; i++) {
    int r2 = tr + 16 * i;   // dst row = src col
    ushort4 o;
    o.x = f2b(tile[tc + 0][r2]);
    o.y = f2b(tile[tc + 1][r2]);
    o.z = f2b(tile[tc + 2][r2]);
    o.w = f2b(tile[tc + 3][r2]);
    *(ushort4*)(dst + (size_t)(cb + r2) * R + rb + tc) = o;
  }
}

// ---------------- shared GEMM main loop: C(128x128) = A(MxK) * Bt(NxK)^T ----------------
// m97 structure: BK=32, global_load_lds x16B, 4 waves in 2x2, 4x4 16x16x32 acc per wave.
__device__ __forceinline__ void gemm_bt_core(const unsigned short* __restrict__ A,
                                             const unsigned short* __restrict__ Bt,
                                             int K, int bm, int bn,
                                             unsigned short* sA, unsigned short* sB,
                                             f32x4 (&acc)[4][4]) {
  const int t = threadIdx.x;
  const int lane = t & 63, w = t >> 6;
  const int wm = (w >> 1) * 64, wn = (w & 1) * 64;
  const int quad = lane >> 4, l16 = lane & 15;

  const int r0 = t >> 2, s0 = (t & 3) * 8;   // 128 rows x 4 segs of 8 bf16
  const int r1 = r0 + 64;
  const unsigned short* Arow0 = A + (size_t)(bm + r0) * K + s0;
  const unsigned short* Arow1 = A + (size_t)(bm + r1) * K + s0;
  const unsigned short* Brow0 = Bt + (size_t)(bn + r0) * K + s0;
  const unsigned short* Brow1 = Bt + (size_t)(bn + r1) * K + s0;
  unsigned short* sA0 = sA + t * 8;
  unsigned short* sA1 = sA + (t + 256) * 8;
  unsigned short* sB0 = sB + t * 8;
  unsigned short* sB1 = sB + (t + 256) * 8;

#pragma unroll 1
  for (int k0 = 0; k0 < K; k0 += 32) {
    gload_lds16(Arow0 + k0, sA0);
    gload_lds16(Arow1 + k0, sA1);
    gload_lds16(Brow0 + k0, sB0);
    gload_lds16(Brow1 + k0, sB1);
    __syncthreads();
    bf16x8 a[4], b[4];
#pragma unroll
    for (int i = 0; i < 4; i++)
      a[i] = *(const bf16x8*)(sA + (wm + i * 16 + l16) * 32 + quad * 8);
#pragma unroll
    for (int j = 0; j < 4; j++)
      b[j] = *(const bf16x8*)(sB + (wn + j * 16 + l16) * 32 + quad * 8);
#pragma unroll
    for (int i = 0; i < 4; i++)
#pragma unroll
      for (int j = 0; j < 4; j++)
        acc[i][j] = mfma16(a[i], b[j], acc[i][j]);
    __syncthreads();
  }
}

// ---------------- GEMM1: qkv = Xb @ Wqkv, fused RoPE epilogue ----------------
// blockIdx.x in [0,48): 128 cols = exactly one (s,h) head chunk. s=0:Q(+scale), 1:K, 2:V(->V^T).
__global__ __launch_bounds__(256) void gemm_qkv_rope(const unsigned short* __restrict__ Xb,
                                                     const unsigned short* __restrict__ Wqt,
                                                     unsigned short* __restrict__ Qd,
                                                     unsigned short* __restrict__ Kd,
                                                     unsigned short* __restrict__ Vtd) {
  __shared__ unsigned short sA[128 * 32];
  __shared__ unsigned short sB[128 * 32];
  f32x4 acc[4][4];
  const f32x4 z = {0.f, 0.f, 0.f, 0.f};
#pragma unroll
  for (int i = 0; i < 4; i++)
#pragma unroll
    for (int j = 0; j < 4; j++) acc[i][j] = z;

  const int bm = blockIdx.y * 128;
  const int bnb = blockIdx.x;
  gemm_bt_core(Xb, Wqt, 2048, bm, bnb * 128, sA, sB, acc);

  const int s = bnb >> 4, h = bnb & 15;
  const int t = threadIdx.x, lane = t & 63, w = t >> 6;
  const int wm = (w >> 1) * 64, wn = (w & 1) * 64;
  const int quad = lane >> 4, l16 = lane & 15;

  if (s < 2) {
    unsigned short* dst = (s == 0) ? Qd : Kd;
    const float scl = (s == 0) ? 0.08838834764831845f : 1.0f;  // 1/sqrt(128) folded into Q
#pragma unroll
    for (int j = 0; j < 4; j++) {
      int d = wn + j * 16 + l16;
      float invf = __expf(-(float)(d >> 1) * 0.14391157f);  // ln(10000)/64
#pragma unroll
      for (int i = 0; i < 4; i++) {
#pragma unroll
        for (int r = 0; r < 4; r++) {
          int m = bm + wm + i * 16 + quad * 4 + r;
          int tpos = m & (TSEQ - 1), b = m >> 11;
          float ang = (float)tpos * invf;
          float sn, cs;
          sincosf(ang, &sn, &cs);
          float v = acc[i][j][r];
          float p = __shfl_xor(v, 1, 64);  // partner column d^1 (adjacent lane)
          float out = (d & 1) ? (v * cs + p * sn) : (v * cs - p * sn);
          out *= scl;
          dst[(((size_t)(b * 16 + h) * TSEQ + tpos) << 7) + d] = f2b(out);
        }
      }
    }
  } else {
    // V stored transposed (B,H,D,T) so attention PV B-operand is LDS-contiguous
#pragma unroll
    for (int j = 0; j < 4; j++) {
      int d = wn + j * 16 + l16;
#pragma unroll
      for (int i = 0; i < 4; i++) {
#pragma unroll
        for (int r = 0; r < 4; r++) {
          int m = bm + wm + i * 16 + quad * 4 + r;
          int tpos = m & (TSEQ - 1), b = m >> 11;
          Vtd[((size_t)(b * 16 + h) * 128 + d) * TSEQ + tpos] = f2b(acc[i][j][r]);
        }
      }
    }
  }
}

// ---------------- Flash attention (causal, online softmax) ----------------
// grid (32 q-tiles, 32 bh). 4 waves x 16 q-rows. Q scale pre-applied.
__global__ __launch_bounds__(256) void attn_kernel(const unsigned short* __restrict__ Q,
                                                   const unsigned short* __restrict__ Kmat,
                                                   const unsigned short* __restrict__ Vt,
                                                   unsigned short* __restrict__ Ob) {
  __shared__ unsigned short sK[64 * 128];   // [key][d]
  __shared__ unsigned short sV[128 * 64];   // [d][key]  (from pre-transposed Vt)
  __shared__ unsigned short sP[4][16 * 64]; // per-wave P round-trip (C-layout -> A-layout)
  const int qb = blockIdx.x, bh = blockIdx.y;
  const int t = threadIdx.x, lane = t & 63, w = t >> 6, quad = lane >> 4, l16 = lane & 15;
  const size_t base = (size_t)bh * TSEQ * 128;
  const unsigned short* Qp = Q + base;
  const unsigned short* Kp = Kmat + base;
  const unsigned short* Vp = Vt + base;

  bf16x8 aq[4];
  {
    int qrow = qb * 64 + w * 16 + l16;
#pragma unroll
    for (int kk = 0; kk < 4; kk++)
      aq[kk] = *(const bf16x8*)(Qp + (size_t)qrow * 128 + kk * 32 + quad * 8);
  }
  const f32x4 z = {0.f, 0.f, 0.f, 0.f};
  f32x4 o[8];
#pragma unroll
  for (int dt = 0; dt < 8; dt++) o[dt] = z;
  float mst[4], lst[4];
#pragma unroll
  for (int r = 0; r < 4; r++) { mst[r] = -1e30f; lst[r] = 0.f; }

  for (int kb = 0; kb <= qb; kb++) {
    const unsigned short* Kt = Kp + (size_t)kb * 64 * 128;
#pragma unroll
    for (int i2 = 0; i2 < 4; i2++) {
      int idx = t + 256 * i2;
      gload_lds16(Kt + (idx >> 4) * 128 + (idx & 15) * 8, sK + idx * 8);
    }
#pragma unroll
    for (int i2 = 0; i2 < 4; i2++) {
      int idx = t + 256 * i2;
      gload_lds16(Vp + (size_t)(idx >> 3) * TSEQ + kb * 64 + (idx & 7) * 8, sV + idx * 8);
    }
    __syncthreads();

    // S = Q @ K^T  (rows: quad*4+r, cols: l16 within nt-tile)
    f32x4 S[4];
#pragma unroll
    for (int nt = 0; nt < 4; nt++) {
      f32x4 sacc = z;
#pragma unroll
      for (int kk = 0; kk < 4; kk++) {
        bf16x8 bk = *(const bf16x8*)(sK + (nt * 16 + l16) * 128 + kk * 32 + quad * 8);
        sacc = mfma16(aq[kk], bk, sacc);
      }
      S[nt] = sacc;
    }
    if (kb == qb) {  // diagonal tile: mask key > q
#pragma unroll
      for (int nt = 0; nt < 4; nt++) {
        int key = kb * 64 + nt * 16 + l16;
        int qg = qb * 64 + w * 16 + quad * 4;
#pragma unroll
        for (int r = 0; r < 4; r++)
          if (key > qg + r) S[nt][r] = -1e30f;
      }
    }
    // online softmax
    float alpha[4];
#pragma unroll
    for (int r = 0; r < 4; r++) {
      float mx = fmaxf(fmaxf(S[0][r], S[1][r]), fmaxf(S[2][r], S[3][r]));
      mx = fmaxf(mx, __shfl_xor(mx, 1, 64));
      mx = fmaxf(mx, __shfl_xor(mx, 2, 64));
      mx = fmaxf(mx, __shfl_xor(mx, 4, 64));
      mx = fmaxf(mx, __shfl_xor(mx, 8, 64));
      float mnew = fmaxf(mst[r], mx);
      alpha[r] = __expf(mst[r] - mnew);
      mst[r] = mnew;
    }
    float rs[4] = {0.f, 0.f, 0.f, 0.f};
#pragma unroll
    for (int nt = 0; nt < 4; nt++)
#pragma unroll
      for (int r = 0; r < 4; r++) {
        float p = __expf(S[nt][r] - mst[r]);
        S[nt][r] = p;
        rs[r] += p;
      }
    unsigned short* myP = sP[w];
#pragma unroll
    for (int r = 0; r < 4; r++) {
      float s4 = rs[r];
      s4 += __shfl_xor(s4, 1, 64);
      s4 += __shfl_xor(s4, 2, 64);
      s4 += __shfl_xor(s4, 4, 64);
      s4 += __shfl_xor(s4, 8, 64);
      lst[r] = lst[r] * alpha[r] + s4;
#pragma unroll
      for (int nt = 0; nt < 4; nt++)
        myP[(quad * 4 + r) * 64 + nt * 16 + l16] = f2b(S[nt][r]);
    }
#pragma unroll
    for (int dt = 0; dt < 8; dt++) {
      f32x4 ov = o[dt];
      ov[0] *= alpha[0]; ov[1] *= alpha[1]; ov[2] *= alpha[2]; ov[3] *= alpha[3];
      o[dt] = ov;
    }
    // O += P @ V  (A from sP in A-layout, B from sV [d][key] contiguous)
#pragma unroll
    for (int kk = 0; kk < 2; kk++) {
      bf16x8 ap = *(const bf16x8*)(myP + l16 * 64 + kk * 32 + quad * 8);
#pragma unroll
      for (int dt = 0; dt < 8; dt++) {
        bf16x8 bv = *(const bf16x8*)(sV + (dt * 16 + l16) * 64 + kk * 32 + quad * 8);
        o[dt] = mfma16(ap, bv, o[dt]);
      }
    }
    __syncthreads();
  }
  // epilogue: O / l -> Ob (b, t, h, d) bf16
  const int b = bh >> 4, h = bh & 15;
#pragma unroll
  for (int dt = 0; dt < 8; dt++) {
#pragma unroll
    for (int r = 0; r < 4; r++) {
      int tq = qb * 64 + w * 16 + quad * 4 + r;
      float val = o[dt][r] / lst[r];
      Ob[(size_t)(b * TSEQ + tq) * 2048 + h * 128 + dt * 16 + l16] = f2b(val);
    }
  }
}

// ---------------- GEMM2: out = Ob @ W_out, fp32 epilogue ----------------
__global__ __launch_bounds__(256) void gemm_out_kernel(const unsigned short* __restrict__ Ob,
                                                       const unsigned short* __restrict__ Wot,
                                                       float* __restrict__ Cout) {
  __shared__ unsigned short sA[128 * 32];
  __shared__ unsigned short sB[128 * 32];
  f32x4 acc[4][4];
  const f32x4 z = {0.f, 0.f, 0.f, 0.f};
#pragma unroll
  for (int i = 0; i < 4; i++)
#pragma unroll
    for (int j = 0; j < 4; j++) acc[i][j] = z;

  const int bm = blockIdx.y * 128, bn = blockIdx.x * 128;
  gemm_bt_core(Ob, Wot, 2048, bm, bn, sA, sB, acc);

  const int t = threadIdx.x, lane = t & 63, w = t >> 6;
  const int wm = (w >> 1) * 64, wn = (w & 1) * 64;
  const int quad = lane >> 4, l16 = lane & 15;
#pragma unroll
  for (int i = 0; i < 4; i++)
#pragma unroll
    for (int j = 0; j < 4; j++)
#pragma unroll
      for (int r = 0; r < 4; r++) {
        int row = bm + wm + i * 16 + quad * 4 + r;
        int col = bn + wn + j * 16 + l16;
        Cout[(size_t)row * 2048 + col] = acc[i][j][r];
      }
}

// ---------------- launch ----------------
extern "C" void kernel_launch(void* const* d_in, const int* in_sizes, int n_in,
                              void* d_out, int out_size, void* d_ws, size_t ws_size,
                              hipStream_t stream) {
  (void)in_sizes; (void)n_in; (void)out_size; (void)ws_size;
  const float* x = (const float*)d_in[0];       // (2,2048,2048)
  const float* Wqkv = (const float*)d_in[1];    // (2048,6144)
  const float* Wout = (const float*)d_in[2];    // (2048,2048)
  float* out = (float*)d_out;                   // (2,2048,2048) fp32
  char* ws = (char*)d_ws;

  unsigned short* Xb  = (unsigned short*)(ws);               // 16 MB  (4096x2048 bf16)
  unsigned short* Wqt = (unsigned short*)(ws + 16777216);    // 24 MB  (6144x2048 bf16, W_qkv^T)
  unsigned short* Wot = (unsigned short*)(ws + 41943040);    // 8 MB   (2048x2048 bf16, W_out^T)
  unsigned short* Qd  = (unsigned short*)(ws + 50331648);    // 16 MB  (B,H,T,D)
  unsigned short* Kd  = (unsigned short*)(ws + 67108864);    // 16 MB  (B,H,T,D)
  unsigned short* Vtd = (unsigned short*)(ws + 83886080);    // 16 MB  (B,H,D,T)
  unsigned short* Obf = (unsigned short*)(ws + 100663296);   // 16 MB  (4096x2048 bf16)

  cast_bf16_kernel<<<8192, 256, 0, stream>>>(x, Xb);
  transpose_cast_kernel<<<dim3(96, 32), 256, 0, stream>>>(Wqkv, Wqt, 2048, 6144);
  transpose_cast_kernel<<<dim3(32, 32), 256, 0, stream>>>(Wout, Wot, 2048, 2048);
  gemm_qkv_rope<<<dim3(48, 32), 256, 0, stream>>>(Xb, Wqt, Qd, Kd, Vtd);
  attn_kernel<<<dim3(32, 32), 256, 0, stream>>>(Qd, Kd, Vtd, Obf);
  gemm_out_kernel<<<dim3(16, 32), 256, 0, stream>>>(Obf, Wot, out);
}

// Round 2
// 625.767 us; speedup vs baseline: 4.0161x; 4.0161x over previous
//
#include <hip/hip_runtime.h>
#include <stdint.h>

// Problem constants: B=2, T=2048, C=2048, H=16, D=128
#define TSEQ 2048

typedef __bf16 bf16x8 __attribute__((ext_vector_type(8)));
typedef float f32x4 __attribute__((ext_vector_type(4)));

typedef const __attribute__((address_space(1))) unsigned int* gas_u32;
typedef __attribute__((address_space(3))) unsigned int* las_u32;

__device__ __forceinline__ f32x4 mfma16(bf16x8 a, bf16x8 b, f32x4 c) {
  return __builtin_amdgcn_mfma_f32_16x16x32_bf16(a, b, c, 0, 0, 0);
}

// fp32 -> bf16 round-to-nearest-even (values are finite; no NaN path needed)
__device__ __forceinline__ unsigned short f2b(float f) {
  unsigned int u = __float_as_uint(f);
  u += 0x7fffu + ((u >> 16) & 1u);
  return (unsigned short)(u >> 16);
}

// async global->LDS, 16B per lane. LDS dest must be wave-uniform base + lane*16.
__device__ __forceinline__ void gload_lds16(const unsigned short* g, unsigned short* l) {
  __builtin_amdgcn_global_load_lds((gas_u32)(const void*)g, (las_u32)(void*)l, 16, 0, 0);
}

// ---------------- cast fp32 -> bf16 (vectorized, exact-size grid) ----------------
__global__ __launch_bounds__(256) void cast_bf16_kernel(const float* __restrict__ src,
                                                        unsigned short* __restrict__ dst) {
  size_t i = ((size_t)blockIdx.x * 256 + threadIdx.x) * 4;
  float4 v = *(const float4*)(src + i);
  ushort4 o;
  o.x = f2b(v.x); o.y = f2b(v.y); o.z = f2b(v.z); o.w = f2b(v.w);
  *(ushort4*)(dst + i) = o;
}

// ---------------- cast + transpose: src (R x Cc) fp32 -> dst (Cc x R) bf16 ----------------
__global__ __launch_bounds__(256) void transpose_cast_kernel(const float* __restrict__ src,
                                                             unsigned short* __restrict__ dst,
                                                             int R, int Cc) {
  __shared__ float tile[64][65];
  int cb = blockIdx.x * 64;
  int rb = blockIdx.y * 64;
  int t = threadIdx.x;
  int tr = t >> 4;          // 0..15
  int tc = (t & 15) * 4;    // 0..60
#pragma unroll
  for (int i = 0; i < 4; i++) {
    int r = tr + 16 * i;
    float4 v = *(const float4*)(src + (size_t)(rb + r) * Cc + cb + tc);
    tile[r][tc + 0] = v.x; tile[r][tc + 1] = v.y;
    tile[r][tc + 2] = v.z; tile[r][tc + 3] = v.w;
  }
  __syncthreads();
#pragma unroll
  for (int i = 0; i < 4; i++) {
    int r2 = tr + 16 * i;   // dst row = src col
    ushort4 o;
    o.x = f2b(tile[tc + 0][r2]);
    o.y = f2b(tile[tc + 1][r2]);
    o.z = f2b(tile[tc + 2][r2]);
    o.w = f2b(tile[tc + 3][r2]);
    *(ushort4*)(dst + (size_t)(cb + r2) * R + rb + tc) = o;
  }
}

// ---------------- shared GEMM main loop: C(128x128) = A(MxK) * Bt(NxK)^T ----------------
// m97 structure: BK=32, global_load_lds x16B, 4 waves in 2x2, 4x4 16x16x32 acc per wave.
__device__ __forceinline__ void gemm_bt_core(const unsigned short* __restrict__ A,
                                             const unsigned short* __restrict__ Bt,
                                             int K, int bm, int bn,
                                             unsigned short* sA, unsigned short* sB,
                                             f32x4 (&acc)[4][4]) {
  const int t = threadIdx.x;
  const int lane = t & 63, w = t >> 6;
  const int wm = (w >> 1) * 64, wn = (w & 1) * 64;
  const int quad = lane >> 4, l16 = lane & 15;

  const int r0 = t >> 2, s0 = (t & 3) * 8;   // 128 rows x 4 segs of 8 bf16
  const int r1 = r0 + 64;
  const unsigned short* Arow0 = A + (size_t)(bm + r0) * K + s0;
  const unsigned short* Arow1 = A + (size_t)(bm + r1) * K + s0;
  const unsigned short* Brow0 = Bt + (size_t)(bn + r0) * K + s0;
  const unsigned short* Brow1 = Bt + (size_t)(bn + r1) * K + s0;
  unsigned short* sA0 = sA + t * 8;
  unsigned short* sA1 = sA + (t + 256) * 8;
  unsigned short* sB0 = sB + t * 8;
  unsigned short* sB1 = sB + (t + 256) * 8;

#pragma unroll 1
  for (int k0 = 0; k0 < K; k0 += 32) {
    gload_lds16(Arow0 + k0, sA0);
    gload_lds16(Arow1 + k0, sA1);
    gload_lds16(Brow0 + k0, sB0);
    gload_lds16(Brow1 + k0, sB1);
    __syncthreads();
    bf16x8 a[4], b[4];
#pragma unroll
    for (int i = 0; i < 4; i++)
      a[i] = *(const bf16x8*)(sA + (wm + i * 16 + l16) * 32 + quad * 8);
#pragma unroll
    for (int j = 0; j < 4; j++)
      b[j] = *(const bf16x8*)(sB + (wn + j * 16 + l16) * 32 + quad * 8);
#pragma unroll
    for (int i = 0; i < 4; i++)
#pragma unroll
      for (int j = 0; j < 4; j++)
        acc[i][j] = mfma16(a[i], b[j], acc[i][j]);
    __syncthreads();
  }
}

// ---------------- GEMM1: qkv = Xb @ Wqkv, fused RoPE epilogue ----------------
// blockIdx.x in [0,48): 128 cols = exactly one (s,h) head chunk. s=0:Q(+scale), 1:K, 2:V(->V^T).
// Epilogue stages the 128x128 bf16 tile in LDS (stride 136 shorts: 16B-aligned rows,
// spreads banks) then writes out with coalesced 16B/lane stores. The previous per-lane
// 2-byte scattered stores caused ~6.3 GB of HBM write traffic (line RMW, no L2 merge).
__global__ __launch_bounds__(256) void gemm_qkv_rope(const unsigned short* __restrict__ Xb,
                                                     const unsigned short* __restrict__ Wqt,
                                                     unsigned short* __restrict__ Qd,
                                                     unsigned short* __restrict__ Kd,
                                                     unsigned short* __restrict__ Vtd) {
  __shared__ unsigned short smem[128 * 136];  // core uses first 8192 shorts (sA+sB)
  unsigned short* sA = smem;
  unsigned short* sB = smem + 4096;
  f32x4 acc[4][4];
  const f32x4 z = {0.f, 0.f, 0.f, 0.f};
#pragma unroll
  for (int i = 0; i < 4; i++)
#pragma unroll
    for (int j = 0; j < 4; j++) acc[i][j] = z;

  const int bm = blockIdx.y * 128;
  const int bnb = blockIdx.x;
  gemm_bt_core(Xb, Wqt, 2048, bm, bnb * 128, sA, sB, acc);

  const int s = bnb >> 4, h = bnb & 15;
  const int t = threadIdx.x, lane = t & 63, w = t >> 6;
  const int wm = (w >> 1) * 64, wn = (w & 1) * 64;
  const int quad = lane >> 4, l16 = lane & 15;
  const int bq = bm >> 11;               // batch index (tiles never straddle batches)
  const int tpos0 = bm & (TSEQ - 1);
  unsigned short* sC = smem;             // reuse staging LDS after final core barrier

  if (s < 2) {
    const float scl = (s == 0) ? 0.08838834764831845f : 1.0f;  // 1/sqrt(128) folded into Q
#pragma unroll
    for (int j = 0; j < 4; j++) {
      int d = wn + j * 16 + l16;
      float invf = __expf(-(float)(d >> 1) * 0.14391157f);  // ln(10000)/64
#pragma unroll
      for (int i = 0; i < 4; i++) {
#pragma unroll
        for (int r = 0; r < 4; r++) {
          int row = wm + i * 16 + quad * 4 + r;   // tile-local tpos
          float ang = (float)(tpos0 + row) * invf;
          float sn, cs;
          __sincosf(ang, &sn, &cs);
          float v = acc[i][j][r];
          float p = __shfl_xor(v, 1, 64);  // partner column d^1 (adjacent lane)
          float outv = (d & 1) ? (v * cs + p * sn) : (v * cs - p * sn);
          sC[row * 136 + d] = f2b(outv * scl);
        }
      }
    }
    __syncthreads();
    unsigned short* dst = (s == 0) ? Qd : Kd;
    size_t gbase = ((size_t)(bq * 16 + h) * TSEQ + tpos0) * 128;
#pragma unroll
    for (int it = 0; it < 8; it++) {
      int c = t + 256 * it;
      int row = c >> 4, off = (c & 15) * 8;
      uint4 vv = *(const uint4*)(sC + row * 136 + off);
      *(uint4*)(dst + gbase + (size_t)row * 128 + off) = vv;
    }
  } else {
    // V stored transposed (B,H,D,T): stage as sC[d][tpos_local], then 16B stores along T
#pragma unroll
    for (int j = 0; j < 4; j++) {
      int d = wn + j * 16 + l16;
#pragma unroll
      for (int i = 0; i < 4; i++)
#pragma unroll
        for (int r = 0; r < 4; r++) {
          int col = wm + i * 16 + quad * 4 + r;
          sC[d * 136 + col] = f2b(acc[i][j][r]);
        }
    }
    __syncthreads();
    size_t gbase = ((size_t)(bq * 16 + h) * 128) * TSEQ + tpos0;
#pragma unroll
    for (int it = 0; it < 8; it++) {
      int c = t + 256 * it;
      int row = c >> 4, off = (c & 15) * 8;   // row = d, off = tpos-local
      uint4 vv = *(const uint4*)(sC + row * 136 + off);
      *(uint4*)(Vtd + gbase + (size_t)row * TSEQ + off) = vv;
    }
  }
}

// ---------------- Flash attention (causal, online softmax) ----------------
// grid (32 q-tiles, 32 bh). 4 waves x 16 q-rows. Q scale pre-applied.
__global__ __launch_bounds__(256) void attn_kernel(const unsigned short* __restrict__ Q,
                                                   const unsigned short* __restrict__ Kmat,
                                                   const unsigned short* __restrict__ Vt,
                                                   unsigned short* __restrict__ Ob) {
  __shared__ unsigned short smem[20480];
  unsigned short* sK = smem;            // 64 x 128 [key][d]    (8192 shorts)
  unsigned short* sV = smem + 8192;     // 128 x 64 [d][key]    (8192 shorts)
  unsigned short* sPb = smem + 16384;   // 4 x (16 x 64) per-wave P round-trip
  const int qb = blockIdx.x, bh = blockIdx.y;
  const int t = threadIdx.x, lane = t & 63, w = t >> 6, quad = lane >> 4, l16 = lane & 15;
  const size_t base = (size_t)bh * TSEQ * 128;
  const unsigned short* Qp = Q + base;
  const unsigned short* Kp = Kmat + base;
  const unsigned short* Vp = Vt + base;

  bf16x8 aq[4];
  {
    int qrow = qb * 64 + w * 16 + l16;
#pragma unroll
    for (int kk = 0; kk < 4; kk++)
      aq[kk] = *(const bf16x8*)(Qp + (size_t)qrow * 128 + kk * 32 + quad * 8);
  }
  const f32x4 z = {0.f, 0.f, 0.f, 0.f};
  f32x4 o[8];
#pragma unroll
  for (int dt = 0; dt < 8; dt++) o[dt] = z;
  float mst[4], lst[4];
#pragma unroll
  for (int r = 0; r < 4; r++) { mst[r] = -1e30f; lst[r] = 0.f; }

  for (int kb = 0; kb <= qb; kb++) {
    const unsigned short* Kt = Kp + (size_t)kb * 64 * 128;
#pragma unroll
    for (int i2 = 0; i2 < 4; i2++) {
      int idx = t + 256 * i2;
      gload_lds16(Kt + (idx >> 4) * 128 + (idx & 15) * 8, sK + idx * 8);
    }
#pragma unroll
    for (int i2 = 0; i2 < 4; i2++) {
      int idx = t + 256 * i2;
      gload_lds16(Vp + (size_t)(idx >> 3) * TSEQ + kb * 64 + (idx & 7) * 8, sV + idx * 8);
    }
    __syncthreads();

    // S = Q @ K^T  (rows: quad*4+r, cols: l16 within nt-tile)
    f32x4 S[4];
#pragma unroll
    for (int nt = 0; nt < 4; nt++) {
      f32x4 sacc = z;
#pragma unroll
      for (int kk = 0; kk < 4; kk++) {
        bf16x8 bk = *(const bf16x8*)(sK + (nt * 16 + l16) * 128 + kk * 32 + quad * 8);
        sacc = mfma16(aq[kk], bk, sacc);
      }
      S[nt] = sacc;
    }
    if (kb == qb) {  // diagonal tile: mask key > q
#pragma unroll
      for (int nt = 0; nt < 4; nt++) {
        int key = kb * 64 + nt * 16 + l16;
        int qg = qb * 64 + w * 16 + quad * 4;
#pragma unroll
        for (int r = 0; r < 4; r++)
          if (key > qg + r) S[nt][r] = -1e30f;
      }
    }
    // online softmax
    float alpha[4];
#pragma unroll
    for (int r = 0; r < 4; r++) {
      float mx = fmaxf(fmaxf(S[0][r], S[1][r]), fmaxf(S[2][r], S[3][r]));
      mx = fmaxf(mx, __shfl_xor(mx, 1, 64));
      mx = fmaxf(mx, __shfl_xor(mx, 2, 64));
      mx = fmaxf(mx, __shfl_xor(mx, 4, 64));
      mx = fmaxf(mx, __shfl_xor(mx, 8, 64));
      float mnew = fmaxf(mst[r], mx);
      alpha[r] = __expf(mst[r] - mnew);
      mst[r] = mnew;
    }
    float rs[4] = {0.f, 0.f, 0.f, 0.f};
#pragma unroll
    for (int nt = 0; nt < 4; nt++)
#pragma unroll
      for (int r = 0; r < 4; r++) {
        float p = __expf(S[nt][r] - mst[r]);
        S[nt][r] = p;
        rs[r] += p;
      }
    unsigned short* myP = sPb + w * 1024;
#pragma unroll
    for (int r = 0; r < 4; r++) {
      float s4 = rs[r];
      s4 += __shfl_xor(s4, 1, 64);
      s4 += __shfl_xor(s4, 2, 64);
      s4 += __shfl_xor(s4, 4, 64);
      s4 += __shfl_xor(s4, 8, 64);
      lst[r] = lst[r] * alpha[r] + s4;
#pragma unroll
      for (int nt = 0; nt < 4; nt++)
        myP[(quad * 4 + r) * 64 + nt * 16 + l16] = f2b(S[nt][r]);
    }
#pragma unroll
    for (int dt = 0; dt < 8; dt++) {
      f32x4 ov = o[dt];
      ov[0] *= alpha[0]; ov[1] *= alpha[1]; ov[2] *= alpha[2]; ov[3] *= alpha[3];
      o[dt] = ov;
    }
    // O += P @ V  (A from sP in A-layout, B from sV [d][key] contiguous)
#pragma unroll
    for (int kk = 0; kk < 2; kk++) {
      bf16x8 ap = *(const bf16x8*)(myP + l16 * 64 + kk * 32 + quad * 8);
#pragma unroll
      for (int dt = 0; dt < 8; dt++) {
        bf16x8 bv = *(const bf16x8*)(sV + (dt * 16 + l16) * 64 + kk * 32 + quad * 8);
        o[dt] = mfma16(ap, bv, o[dt]);
      }
    }
    __syncthreads();
  }
  // epilogue: O / l -> LDS (stride 136) -> coalesced 16B stores to Ob (b, t, h, d)
  unsigned short* sO = smem;   // 64 x 136, fits in sK+sV region (safe after final barrier)
#pragma unroll
  for (int dt = 0; dt < 8; dt++)
#pragma unroll
    for (int r = 0; r < 4; r++) {
      int row = w * 16 + quad * 4 + r;
      sO[row * 136 + dt * 16 + l16] = f2b(o[dt][r] / lst[r]);
    }
  __syncthreads();
  const int b = bh >> 4, h = bh & 15;
#pragma unroll
  for (int it = 0; it < 4; it++) {
    int c = t + 256 * it;
    int row = c >> 4, off = (c & 15) * 8;
    uint4 vv = *(const uint4*)(sO + row * 136 + off);
    *(uint4*)(Ob + (size_t)(b * TSEQ + qb * 64 + row) * 2048 + h * 128 + off) = vv;
  }
}

// ---------------- GEMM2: out = Ob @ W_out, fp32 epilogue ----------------
__global__ __launch_bounds__(256) void gemm_out_kernel(const unsigned short* __restrict__ Ob,
                                                       const unsigned short* __restrict__ Wot,
                                                       float* __restrict__ Cout) {
  __shared__ unsigned short sA[128 * 32];
  __shared__ unsigned short sB[128 * 32];
  f32x4 acc[4][4];
  const f32x4 z = {0.f, 0.f, 0.f, 0.f};
#pragma unroll
  for (int i = 0; i < 4; i++)
#pragma unroll
    for (int j = 0; j < 4; j++) acc[i][j] = z;

  const int bm = blockIdx.y * 128, bn = blockIdx.x * 128;
  gemm_bt_core(Ob, Wot, 2048, bm, bn, sA, sB, acc);

  const int t = threadIdx.x, lane = t & 63, w = t >> 6;
  const int wm = (w >> 1) * 64, wn = (w & 1) * 64;
  const int quad = lane >> 4, l16 = lane & 15;
#pragma unroll
  for (int i = 0; i < 4; i++)
#pragma unroll
    for (int j = 0; j < 4; j++)
#pragma unroll
      for (int r = 0; r < 4; r++) {
        int row = bm + wm + i * 16 + quad * 4 + r;
        int col = bn + wn + j * 16 + l16;
        Cout[(size_t)row * 2048 + col] = acc[i][j][r];
      }
}

// ---------------- launch ----------------
extern "C" void kernel_launch(void* const* d_in, const int* in_sizes, int n_in,
                              void* d_out, int out_size, void* d_ws, size_t ws_size,
                              hipStream_t stream) {
  (void)in_sizes; (void)n_in; (void)out_size; (void)ws_size;
  const float* x = (const float*)d_in[0];       // (2,2048,2048)
  const float* Wqkv = (const float*)d_in[1];    // (2048,6144)
  const float* Wout = (const float*)d_in[2];    // (2048,2048)
  float* out = (float*)d_out;                   // (2,2048,2048) fp32
  char* ws = (char*)d_ws;

  unsigned short* Xb  = (unsigned short*)(ws);               // 16 MB  (4096x2048 bf16)
  unsigned short* Wqt = (unsigned short*)(ws + 16777216);    // 24 MB  (6144x2048 bf16, W_qkv^T)
  unsigned short* Wot = (unsigned short*)(ws + 41943040);    // 8 MB   (2048x2048 bf16, W_out^T)
  unsigned short* Qd  = (unsigned short*)(ws + 50331648);    // 16 MB  (B,H,T,D)
  unsigned short* Kd  = (unsigned short*)(ws + 67108864);    // 16 MB  (B,H,T,D)
  unsigned short* Vtd = (unsigned short*)(ws + 83886080);    // 16 MB  (B,H,D,T)
  unsigned short* Obf = (unsigned short*)(ws + 100663296);   // 16 MB  (4096x2048 bf16)

  cast_bf16_kernel<<<8192, 256, 0, stream>>>(x, Xb);
  transpose_cast_kernel<<<dim3(96, 32), 256, 0, stream>>>(Wqkv, Wqt, 2048, 6144);
  transpose_cast_kernel<<<dim3(32, 32), 256, 0, stream>>>(Wout, Wot, 2048, 2048);
  gemm_qkv_rope<<<dim3(48, 32), 256, 0, stream>>>(Xb, Wqt, Qd, Kd, Vtd);
  attn_kernel<<<dim3(32, 32), 256, 0, stream>>>(Qd, Kd, Vtd, Obf);
  gemm_out_kernel<<<dim3(16, 32), 256, 0, stream>>>(Obf, Wot, out);
}

// Round 3
// 441.165 us; speedup vs baseline: 5.6967x; 1.4184x over previous
//
#include <hip/hip_runtime.h>
#include <stdint.h>

// Problem constants: B=2, T=2048, C=2048, H=16, D=128
#define TSEQ 2048

typedef __bf16 bf16x8 __attribute__((ext_vector_type(8)));
typedef float f32x4 __attribute__((ext_vector_type(4)));

typedef const __attribute__((address_space(1))) unsigned int* gas_u32;
typedef __attribute__((address_space(3))) unsigned int* las_u32;

__device__ __forceinline__ f32x4 mfma16(bf16x8 a, bf16x8 b, f32x4 c) {
  return __builtin_amdgcn_mfma_f32_16x16x32_bf16(a, b, c, 0, 0, 0);
}

// fp32 -> bf16 round-to-nearest-even (values are finite; no NaN path needed)
__device__ __forceinline__ unsigned short f2b(float f) {
  unsigned int u = __float_as_uint(f);
  u += 0x7fffu + ((u >> 16) & 1u);
  return (unsigned short)(u >> 16);
}

// async global->LDS, 16B per lane. LDS dest must be wave-uniform base + lane*16.
__device__ __forceinline__ void gload_lds16(const unsigned short* g, unsigned short* l) {
  __builtin_amdgcn_global_load_lds((gas_u32)(const void*)g, (las_u32)(void*)l, 16, 0, 0);
}

// ---------------- cast fp32 -> bf16 (vectorized, exact-size grid) ----------------
__global__ __launch_bounds__(256) void cast_bf16_kernel(const float* __restrict__ src,
                                                        unsigned short* __restrict__ dst) {
  size_t i = ((size_t)blockIdx.x * 256 + threadIdx.x) * 4;
  float4 v = *(const float4*)(src + i);
  ushort4 o;
  o.x = f2b(v.x); o.y = f2b(v.y); o.z = f2b(v.z); o.w = f2b(v.w);
  *(ushort4*)(dst + i) = o;
}

// ---------------- cast + transpose: src (R x Cc) fp32 -> dst (Cc x R) bf16 ----------------
__global__ __launch_bounds__(256) void transpose_cast_kernel(const float* __restrict__ src,
                                                             unsigned short* __restrict__ dst,
                                                             int R, int Cc) {
  __shared__ float tile[64][65];
  int cb = blockIdx.x * 64;
  int rb = blockIdx.y * 64;
  int t = threadIdx.x;
  int tr = t >> 4;          // 0..15
  int tc = (t & 15) * 4;    // 0..60
#pragma unroll
  for (int i = 0; i < 4; i++) {
    int r = tr + 16 * i;
    float4 v = *(const float4*)(src + (size_t)(rb + r) * Cc + cb + tc);
    tile[r][tc + 0] = v.x; tile[r][tc + 1] = v.y;
    tile[r][tc + 2] = v.z; tile[r][tc + 3] = v.w;
  }
  __syncthreads();
#pragma unroll
  for (int i = 0; i < 4; i++) {
    int r2 = tr + 16 * i;   // dst row = src col
    ushort4 o;
    o.x = f2b(tile[tc + 0][r2]);
    o.y = f2b(tile[tc + 1][r2]);
    o.z = f2b(tile[tc + 2][r2]);
    o.w = f2b(tile[tc + 3][r2]);
    *(ushort4*)(dst + (size_t)(cb + r2) * R + rb + tc) = o;
  }
}

// ---------------- shared GEMM main loop: C(128x128) = A(MxK) * Bt(NxK)^T ----------------
// m97 structure: BK=32, global_load_lds x16B, 4 waves in 2x2, 4x4 16x16x32 acc per wave.
__device__ __forceinline__ void gemm_bt_core(const unsigned short* __restrict__ A,
                                             const unsigned short* __restrict__ Bt,
                                             int K, int bm, int bn,
                                             unsigned short* sA, unsigned short* sB,
                                             f32x4 (&acc)[4][4]) {
  const int t = threadIdx.x;
  const int lane = t & 63, w = t >> 6;
  const int wm = (w >> 1) * 64, wn = (w & 1) * 64;
  const int quad = lane >> 4, l16 = lane & 15;

  const int r0 = t >> 2, s0 = (t & 3) * 8;   // 128 rows x 4 segs of 8 bf16
  const int r1 = r0 + 64;
  const unsigned short* Arow0 = A + (size_t)(bm + r0) * K + s0;
  const unsigned short* Arow1 = A + (size_t)(bm + r1) * K + s0;
  const unsigned short* Brow0 = Bt + (size_t)(bn + r0) * K + s0;
  const unsigned short* Brow1 = Bt + (size_t)(bn + r1) * K + s0;
  unsigned short* sA0 = sA + t * 8;
  unsigned short* sA1 = sA + (t + 256) * 8;
  unsigned short* sB0 = sB + t * 8;
  unsigned short* sB1 = sB + (t + 256) * 8;

#pragma unroll 1
  for (int k0 = 0; k0 < K; k0 += 32) {
    gload_lds16(Arow0 + k0, sA0);
    gload_lds16(Arow1 + k0, sA1);
    gload_lds16(Brow0 + k0, sB0);
    gload_lds16(Brow1 + k0, sB1);
    __syncthreads();
    bf16x8 a[4], b[4];
#pragma unroll
    for (int i = 0; i < 4; i++)
      a[i] = *(const bf16x8*)(sA + (wm + i * 16 + l16) * 32 + quad * 8);
#pragma unroll
    for (int j = 0; j < 4; j++)
      b[j] = *(const bf16x8*)(sB + (wn + j * 16 + l16) * 32 + quad * 8);
#pragma unroll
    for (int i = 0; i < 4; i++)
#pragma unroll
      for (int j = 0; j < 4; j++)
        acc[i][j] = mfma16(a[i], b[j], acc[i][j]);
    __syncthreads();
  }
}

// ---------------- GEMM1: qkv = Xb @ Wqkv, fused RoPE epilogue ----------------
// blockIdx.x in [0,48): 128 cols = exactly one (s,h) head chunk. s=0:Q(+scale), 1:K, 2:V(->V^T).
// Epilogue stages the 128x128 bf16 tile in LDS (stride 136 shorts) then writes out with
// coalesced 16B/lane stores (2-byte scattered stores caused ~6.3 GB of HBM write RMW).
__global__ __launch_bounds__(256) void gemm_qkv_rope(const unsigned short* __restrict__ Xb,
                                                     const unsigned short* __restrict__ Wqt,
                                                     unsigned short* __restrict__ Qd,
                                                     unsigned short* __restrict__ Kd,
                                                     unsigned short* __restrict__ Vtd) {
  __shared__ unsigned short smem[128 * 136];  // core uses first 8192 shorts (sA+sB)
  unsigned short* sA = smem;
  unsigned short* sB = smem + 4096;
  f32x4 acc[4][4];
  const f32x4 z = {0.f, 0.f, 0.f, 0.f};
#pragma unroll
  for (int i = 0; i < 4; i++)
#pragma unroll
    for (int j = 0; j < 4; j++) acc[i][j] = z;

  const int bm = blockIdx.y * 128;
  const int bnb = blockIdx.x;
  gemm_bt_core(Xb, Wqt, 2048, bm, bnb * 128, sA, sB, acc);

  const int s = bnb >> 4, h = bnb & 15;
  const int t = threadIdx.x, lane = t & 63, w = t >> 6;
  const int wm = (w >> 1) * 64, wn = (w & 1) * 64;
  const int quad = lane >> 4, l16 = lane & 15;
  const int bq = bm >> 11;               // batch index (tiles never straddle batches)
  const int tpos0 = bm & (TSEQ - 1);
  unsigned short* sC = smem;             // reuse staging LDS after final core barrier

  if (s < 2) {
    const float scl = (s == 0) ? 0.08838834764831845f : 1.0f;  // 1/sqrt(128) folded into Q
#pragma unroll
    for (int j = 0; j < 4; j++) {
      int d = wn + j * 16 + l16;
      float invf = __expf(-(float)(d >> 1) * 0.14391157f);  // ln(10000)/64
#pragma unroll
      for (int i = 0; i < 4; i++) {
#pragma unroll
        for (int r = 0; r < 4; r++) {
          int row = wm + i * 16 + quad * 4 + r;   // tile-local tpos
          float ang = (float)(tpos0 + row) * invf;
          float sn, cs;
          __sincosf(ang, &sn, &cs);
          float v = acc[i][j][r];
          float p = __shfl_xor(v, 1, 64);  // partner column d^1 (adjacent lane)
          float outv = (d & 1) ? (v * cs + p * sn) : (v * cs - p * sn);
          sC[row * 136 + d] = f2b(outv * scl);
        }
      }
    }
    __syncthreads();
    unsigned short* dst = (s == 0) ? Qd : Kd;
    size_t gbase = ((size_t)(bq * 16 + h) * TSEQ + tpos0) * 128;
#pragma unroll
    for (int it = 0; it < 8; it++) {
      int c = t + 256 * it;
      int row = c >> 4, off = (c & 15) * 8;
      uint4 vv = *(const uint4*)(sC + row * 136 + off);
      *(uint4*)(dst + gbase + (size_t)row * 128 + off) = vv;
    }
  } else {
    // V stored transposed (B,H,D,T): stage as sC[d][tpos_local], then 16B stores along T
#pragma unroll
    for (int j = 0; j < 4; j++) {
      int d = wn + j * 16 + l16;
#pragma unroll
      for (int i = 0; i < 4; i++)
#pragma unroll
        for (int r = 0; r < 4; r++) {
          int col = wm + i * 16 + quad * 4 + r;
          sC[d * 136 + col] = f2b(acc[i][j][r]);
        }
    }
    __syncthreads();
    size_t gbase = ((size_t)(bq * 16 + h) * 128) * TSEQ + tpos0;
#pragma unroll
    for (int it = 0; it < 8; it++) {
      int c = t + 256 * it;
      int row = c >> 4, off = (c & 15) * 8;   // row = d, off = tpos-local
      uint4 vv = *(const uint4*)(sC + row * 136 + off);
      *(uint4*)(Vtd + gbase + (size_t)row * TSEQ + off) = vv;
    }
  }
}

// ---------------- Flash attention v2 ----------------
// Pair-balanced causal schedule: block (pair, bh) handles q-tiles qA=pair, qB=31-pair
// (33 tile-computes per block, K/V tile at each kb loaded ONCE for both tiles).
// Double-buffered K/V in LDS (prefetch issued after the top barrier so it overlaps
// compute); XOR-swizzled 16B-chunk placement kills the 16-way bank conflicts
// (row strides 256B/128B put all 16 l16-lanes in one bank otherwise).
// LDS: 2*(8192+8192) + 4*16*72 = 74752 B -> 2 blocks/CU; VGPR capped via (256,2).
__global__ __launch_bounds__(256, 2) void attn_kernel(const unsigned short* __restrict__ Q,
                                                      const unsigned short* __restrict__ Kmat,
                                                      const unsigned short* __restrict__ Vt,
                                                      unsigned short* __restrict__ Ob) {
  __shared__ unsigned short smem[37376];
  const int pair = blockIdx.x, bh = blockIdx.y;
  const int qA = pair, qB = 31 - pair;
  const int t = threadIdx.x, lane = t & 63, w = t >> 6, quad = lane >> 4, l16 = lane & 15;
  const size_t base = (size_t)bh * TSEQ * 128;
  const unsigned short* Qp = Q + base;
  const unsigned short* Kp = Kmat + base;
  const unsigned short* Vp = Vt + base;
  unsigned short* myP = smem + 32768 + w * 1152;   // 16 x 72 per wave

  bf16x8 aqA[4], aqB[4];
  {
    int qrA = qA * 64 + w * 16 + l16;
    int qrB = qB * 64 + w * 16 + l16;
#pragma unroll
    for (int kk = 0; kk < 4; kk++) {
      aqA[kk] = *(const bf16x8*)(Qp + (size_t)qrA * 128 + kk * 32 + quad * 8);
      aqB[kk] = *(const bf16x8*)(Qp + (size_t)qrB * 128 + kk * 32 + quad * 8);
    }
  }
  const f32x4 z = {0.f, 0.f, 0.f, 0.f};
  f32x4 oA[8], oB[8];
  float mA[4], lA[4], mB[4], lB[4];
#pragma unroll
  for (int dt = 0; dt < 8; dt++) { oA[dt] = z; oB[dt] = z; }
#pragma unroll
  for (int r = 0; r < 4; r++) { mA[r] = -1e30f; lA[r] = 0.f; mB[r] = -1e30f; lB[r] = 0.f; }

  // swizzled K/V tile load: chunk c of row r lives at slot (c ^ (r&7))
  auto load_tiles = [&](int kb, int buf) {
    unsigned short* bK = smem + buf * 16384;
    unsigned short* bV = bK + 8192;
    const unsigned short* Kt = Kp + (size_t)kb * 64 * 128;
#pragma unroll
    for (int i2 = 0; i2 < 4; i2++) {
      int idx = t + 256 * i2;                       // LDS linear 16B-chunk
      int r = idx >> 4, cS = idx & 15;
      int c = cS ^ (r & 7);
      gload_lds16(Kt + r * 128 + c * 8, bK + idx * 8);
    }
#pragma unroll
    for (int i2 = 0; i2 < 4; i2++) {
      int idx = t + 256 * i2;
      int r = idx >> 3, cS = idx & 7;               // r = d index
      int c = cS ^ (r & 7);
      gload_lds16(Vp + (size_t)r * TSEQ + kb * 64 + c * 8, bV + idx * 8);
    }
  };

  auto process = [&](bf16x8 (&aq)[4], f32x4 (&o)[8], float (&mst)[4], float (&lst)[4],
                     int qb, int kb, const unsigned short* bK, const unsigned short* bV) {
    f32x4 S[4];
#pragma unroll
    for (int nt = 0; nt < 4; nt++) {
      f32x4 sacc = z;
#pragma unroll
      for (int kk = 0; kk < 4; kk++) {
        const unsigned short* p =
            bK + (nt * 16 + l16) * 128 + (((kk * 4 + quad) ^ (l16 & 7)) * 8);
        sacc = mfma16(aq[kk], *(const bf16x8*)p, sacc);
      }
      S[nt] = sacc;
    }
    if (kb == qb) {  // diagonal tile: mask key > q
      int qg = qb * 64 + w * 16 + quad * 4;
#pragma unroll
      for (int nt = 0; nt < 4; nt++) {
        int key = kb * 64 + nt * 16 + l16;
#pragma unroll
        for (int r = 0; r < 4; r++)
          if (key > qg + r) S[nt][r] = -1e30f;
      }
    }
    float alpha[4];
#pragma unroll
    for (int r = 0; r < 4; r++) {
      float mx = fmaxf(fmaxf(S[0][r], S[1][r]), fmaxf(S[2][r], S[3][r]));
      mx = fmaxf(mx, __shfl_xor(mx, 1, 64));
      mx = fmaxf(mx, __shfl_xor(mx, 2, 64));
      mx = fmaxf(mx, __shfl_xor(mx, 4, 64));
      mx = fmaxf(mx, __shfl_xor(mx, 8, 64));
      float mnew = fmaxf(mst[r], mx);
      alpha[r] = __expf(mst[r] - mnew);
      mst[r] = mnew;
    }
    float rs[4] = {0.f, 0.f, 0.f, 0.f};
#pragma unroll
    for (int nt = 0; nt < 4; nt++)
#pragma unroll
      for (int r = 0; r < 4; r++) {
        float p = __expf(S[nt][r] - mst[r]);
        S[nt][r] = p;
        rs[r] += p;
      }
#pragma unroll
    for (int r = 0; r < 4; r++) {
      float s4 = rs[r];
      s4 += __shfl_xor(s4, 1, 64);
      s4 += __shfl_xor(s4, 2, 64);
      s4 += __shfl_xor(s4, 4, 64);
      s4 += __shfl_xor(s4, 8, 64);
      lst[r] = lst[r] * alpha[r] + s4;
#pragma unroll
      for (int nt = 0; nt < 4; nt++)
        myP[(quad * 4 + r) * 72 + nt * 16 + l16] = f2b(S[nt][r]);
    }
#pragma unroll
    for (int dt = 0; dt < 8; dt++) {
      f32x4 ov = o[dt];
      ov[0] *= alpha[0]; ov[1] *= alpha[1]; ov[2] *= alpha[2]; ov[3] *= alpha[3];
      o[dt] = ov;
    }
#pragma unroll
    for (int kk = 0; kk < 2; kk++) {
      bf16x8 ap = *(const bf16x8*)(myP + l16 * 72 + kk * 32 + quad * 8);
#pragma unroll
      for (int dt = 0; dt < 8; dt++) {
        const unsigned short* p =
            bV + (dt * 16 + l16) * 64 + (((kk * 4 + quad) ^ (l16 & 7)) * 8);
        o[dt] = mfma16(ap, *(const bf16x8*)p, o[dt]);
      }
    }
  };

  load_tiles(0, 0);
#pragma unroll 1
  for (int kb = 0; kb <= qB; kb++) {
    __syncthreads();                      // drains loads for current buffer
    if (kb < qB) load_tiles(kb + 1, (kb + 1) & 1);  // prefetch overlaps compute below
    const unsigned short* bK = smem + (kb & 1) * 16384;
    const unsigned short* bV = bK + 8192;
    process(aqB, oB, mB, lB, qB, kb, bK, bV);
    if (kb <= qA) process(aqA, oA, mA, lA, qA, kb, bK, bV);
  }

  // epilogue: both tiles -> LDS (stride 136) -> coalesced 16B stores to Ob (b,t,h,d)
  __syncthreads();                        // all waves done reading K/V buffers
  unsigned short* sOA = smem;             // 64 x 136
  unsigned short* sOB = smem + 8704;      // 64 x 136
#pragma unroll
  for (int dt = 0; dt < 8; dt++)
#pragma unroll
    for (int r = 0; r < 4; r++) {
      int row = w * 16 + quad * 4 + r;
      sOA[row * 136 + dt * 16 + l16] = f2b(oA[dt][r] / lA[r]);
      sOB[row * 136 + dt * 16 + l16] = f2b(oB[dt][r] / lB[r]);
    }
  __syncthreads();
  const int b = bh >> 4, h = bh & 15;
#pragma unroll
  for (int it = 0; it < 4; it++) {
    int c = t + 256 * it;
    int row = c >> 4, off = (c & 15) * 8;
    uint4 va = *(const uint4*)(sOA + row * 136 + off);
    *(uint4*)(Ob + (size_t)(b * TSEQ + qA * 64 + row) * 2048 + h * 128 + off) = va;
    uint4 vb = *(const uint4*)(sOB + row * 136 + off);
    *(uint4*)(Ob + (size_t)(b * TSEQ + qB * 64 + row) * 2048 + h * 128 + off) = vb;
  }
}

// ---------------- GEMM2: out = Ob @ W_out, fp32 epilogue ----------------
__global__ __launch_bounds__(256) void gemm_out_kernel(const unsigned short* __restrict__ Ob,
                                                       const unsigned short* __restrict__ Wot,
                                                       float* __restrict__ Cout) {
  __shared__ unsigned short sA[128 * 32];
  __shared__ unsigned short sB[128 * 32];
  f32x4 acc[4][4];
  const f32x4 z = {0.f, 0.f, 0.f, 0.f};
#pragma unroll
  for (int i = 0; i < 4; i++)
#pragma unroll
    for (int j = 0; j < 4; j++) acc[i][j] = z;

  const int bm = blockIdx.y * 128, bn = blockIdx.x * 128;
  gemm_bt_core(Ob, Wot, 2048, bm, bn, sA, sB, acc);

  const int t = threadIdx.x, lane = t & 63, w = t >> 6;
  const int wm = (w >> 1) * 64, wn = (w & 1) * 64;
  const int quad = lane >> 4, l16 = lane & 15;
#pragma unroll
  for (int i = 0; i < 4; i++)
#pragma unroll
    for (int j = 0; j < 4; j++)
#pragma unroll
      for (int r = 0; r < 4; r++) {
        int row = bm + wm + i * 16 + quad * 4 + r;
        int col = bn + wn + j * 16 + l16;
        Cout[(size_t)row * 2048 + col] = acc[i][j][r];
      }
}

// ---------------- launch ----------------
extern "C" void kernel_launch(void* const* d_in, const int* in_sizes, int n_in,
                              void* d_out, int out_size, void* d_ws, size_t ws_size,
                              hipStream_t stream) {
  (void)in_sizes; (void)n_in; (void)out_size; (void)ws_size;
  const float* x = (const float*)d_in[0];       // (2,2048,2048)
  const float* Wqkv = (const float*)d_in[1];    // (2048,6144)
  const float* Wout = (const float*)d_in[2];    // (2048,2048)
  float* out = (float*)d_out;                   // (2,2048,2048) fp32
  char* ws = (char*)d_ws;

  unsigned short* Xb  = (unsigned short*)(ws);               // 16 MB  (4096x2048 bf16)
  unsigned short* Wqt = (unsigned short*)(ws + 16777216);    // 24 MB  (6144x2048 bf16, W_qkv^T)
  unsigned short* Wot = (unsigned short*)(ws + 41943040);    // 8 MB   (2048x2048 bf16, W_out^T)
  unsigned short* Qd  = (unsigned short*)(ws + 50331648);    // 16 MB  (B,H,T,D)
  unsigned short* Kd  = (unsigned short*)(ws + 67108864);    // 16 MB  (B,H,T,D)
  unsigned short* Vtd = (unsigned short*)(ws + 83886080);    // 16 MB  (B,H,D,T)
  unsigned short* Obf = (unsigned short*)(ws + 100663296);   // 16 MB  (4096x2048 bf16)

  cast_bf16_kernel<<<8192, 256, 0, stream>>>(x, Xb);
  transpose_cast_kernel<<<dim3(96, 32), 256, 0, stream>>>(Wqkv, Wqt, 2048, 6144);
  transpose_cast_kernel<<<dim3(32, 32), 256, 0, stream>>>(Wout, Wot, 2048, 2048);
  gemm_qkv_rope<<<dim3(48, 32), 256, 0, stream>>>(Xb, Wqt, Qd, Kd, Vtd);
  attn_kernel<<<dim3(16, 32), 256, 0, stream>>>(Qd, Kd, Vtd, Obf);
  gemm_out_kernel<<<dim3(16, 32), 256, 0, stream>>>(Obf, Wot, out);
}

// Round 4
// 403.579 us; speedup vs baseline: 6.2272x; 1.0931x over previous
//
#include <hip/hip_runtime.h>
#include <stdint.h>

// Problem constants: B=2, T=2048, C=2048, H=16, D=128
#define TSEQ 2048

typedef __bf16 bf16x8 __attribute__((ext_vector_type(8)));
typedef float f32x4 __attribute__((ext_vector_type(4)));

typedef const __attribute__((address_space(1))) unsigned int* gas_u32;
typedef __attribute__((address_space(3))) unsigned int* las_u32;

__device__ __forceinline__ f32x4 mfma16(bf16x8 a, bf16x8 b, f32x4 c) {
  return __builtin_amdgcn_mfma_f32_16x16x32_bf16(a, b, c, 0, 0, 0);
}

// fp32 -> bf16 round-to-nearest-even (values are finite; no NaN path needed)
__device__ __forceinline__ unsigned short f2b(float f) {
  unsigned int u = __float_as_uint(f);
  u += 0x7fffu + ((u >> 16) & 1u);
  return (unsigned short)(u >> 16);
}

// async global->LDS, 16B per lane. LDS dest must be wave-uniform base + lane*16.
__device__ __forceinline__ void gload_lds16(const unsigned short* g, unsigned short* l) {
  __builtin_amdgcn_global_load_lds((gas_u32)(const void*)g, (las_u32)(void*)l, 16, 0, 0);
}

// ---------------- cast fp32 -> bf16 (vectorized, exact-size grid) ----------------
__global__ __launch_bounds__(256) void cast_bf16_kernel(const float* __restrict__ src,
                                                        unsigned short* __restrict__ dst) {
  size_t i = ((size_t)blockIdx.x * 256 + threadIdx.x) * 4;
  float4 v = *(const float4*)(src + i);
  ushort4 o;
  o.x = f2b(v.x); o.y = f2b(v.y); o.z = f2b(v.z); o.w = f2b(v.w);
  *(ushort4*)(dst + i) = o;
}

// ---------------- cast + transpose: src (R x Cc) fp32 -> dst (Cc x R) bf16 ----------------
__global__ __launch_bounds__(256) void transpose_cast_kernel(const float* __restrict__ src,
                                                             unsigned short* __restrict__ dst,
                                                             int R, int Cc) {
  __shared__ float tile[64][65];
  int cb = blockIdx.x * 64;
  int rb = blockIdx.y * 64;
  int t = threadIdx.x;
  int tr = t >> 4;          // 0..15
  int tc = (t & 15) * 4;    // 0..60
#pragma unroll
  for (int i = 0; i < 4; i++) {
    int r = tr + 16 * i;
    float4 v = *(const float4*)(src + (size_t)(rb + r) * Cc + cb + tc);
    tile[r][tc + 0] = v.x; tile[r][tc + 1] = v.y;
    tile[r][tc + 2] = v.z; tile[r][tc + 3] = v.w;
  }
  __syncthreads();
#pragma unroll
  for (int i = 0; i < 4; i++) {
    int r2 = tr + 16 * i;   // dst row = src col
    ushort4 o;
    o.x = f2b(tile[tc + 0][r2]);
    o.y = f2b(tile[tc + 1][r2]);
    o.z = f2b(tile[tc + 2][r2]);
    o.w = f2b(tile[tc + 3][r2]);
    *(ushort4*)(dst + (size_t)(cb + r2) * R + rb + tc) = o;
  }
}

// ---------------- shared GEMM main loop (double-buffered): C(128x128) = A * Bt^T --------
// m97 structure + dbuf: BK=32, global_load_lds x16B, 4 waves in 2x2, 4x4 16x16x32 acc.
// One barrier per K-step; prefetch for step k+1 issued right after the barrier so the
// vmcnt(0)-at-barrier drain sees loads that had a full compute phase to land.
// sm layout: buf b at sm + b*8192 shorts (sA 4096 | sB 4096). Trailing barrier included,
// so callers may reuse sm immediately after return.
__device__ __forceinline__ void gemm_bt_core_db(const unsigned short* __restrict__ A,
                                                const unsigned short* __restrict__ Bt,
                                                int K, int bm, int bn,
                                                unsigned short* sm,
                                                f32x4 (&acc)[4][4]) {
  const int t = threadIdx.x;
  const int lane = t & 63, w = t >> 6;
  const int wm = (w >> 1) * 64, wn = (w & 1) * 64;
  const int quad = lane >> 4, l16 = lane & 15;

  const int r0 = t >> 2, s0 = (t & 3) * 8;   // 128 rows x 4 segs of 8 bf16
  const unsigned short* Arow0 = A + (size_t)(bm + r0) * K + s0;
  const unsigned short* Arow1 = Arow0 + (size_t)64 * K;
  const unsigned short* Brow0 = Bt + (size_t)(bn + r0) * K + s0;
  const unsigned short* Brow1 = Brow0 + (size_t)64 * K;

  auto stage = [&](int k0, int buf) {
    unsigned short* sA = sm + buf * 8192;
    unsigned short* sB = sA + 4096;
    gload_lds16(Arow0 + k0, sA + t * 8);
    gload_lds16(Arow1 + k0, sA + (t + 256) * 8);
    gload_lds16(Brow0 + k0, sB + t * 8);
    gload_lds16(Brow1 + k0, sB + (t + 256) * 8);
  };

  stage(0, 0);
  const int nIter = K >> 5;
#pragma unroll 1
  for (int it = 0; it < nIter; it++) {
    __syncthreads();                       // drains loads for buffer it&1
    if (it + 1 < nIter) stage((it + 1) * 32, (it + 1) & 1);  // overlaps compute below
    const unsigned short* sA = sm + (it & 1) * 8192;
    const unsigned short* sB = sA + 4096;
    bf16x8 a[4], b[4];
#pragma unroll
    for (int i = 0; i < 4; i++)
      a[i] = *(const bf16x8*)(sA + (wm + i * 16 + l16) * 32 + quad * 8);
#pragma unroll
    for (int j = 0; j < 4; j++)
      b[j] = *(const bf16x8*)(sB + (wn + j * 16 + l16) * 32 + quad * 8);
#pragma unroll
    for (int i = 0; i < 4; i++)
#pragma unroll
      for (int j = 0; j < 4; j++)
        acc[i][j] = mfma16(a[i], b[j], acc[i][j]);
  }
  __syncthreads();                         // callers reuse sm right after
}

// ---------------- GEMM1: qkv = Xb @ Wqkv, fused RoPE epilogue ----------------
// blockIdx.x in [0,48): 128 cols = exactly one (s,h) head chunk. s=0:Q(+scale), 1:K, 2:V(->V^T).
// Epilogue stages the 128x128 bf16 tile in LDS (stride 136 shorts) then writes out with
// coalesced 16B/lane stores (2-byte scattered stores caused ~6.3 GB of HBM write RMW).
__global__ __launch_bounds__(256, 4) void gemm_qkv_rope(const unsigned short* __restrict__ Xb,
                                                        const unsigned short* __restrict__ Wqt,
                                                        unsigned short* __restrict__ Qd,
                                                        unsigned short* __restrict__ Kd,
                                                        unsigned short* __restrict__ Vtd) {
  __shared__ unsigned short smem[17408];  // max(core dbuf 16384, epilogue 128*136)
  f32x4 acc[4][4];
  const f32x4 z = {0.f, 0.f, 0.f, 0.f};
#pragma unroll
  for (int i = 0; i < 4; i++)
#pragma unroll
    for (int j = 0; j < 4; j++) acc[i][j] = z;

  const int bm = blockIdx.y * 128;
  const int bnb = blockIdx.x;
  gemm_bt_core_db(Xb, Wqt, 2048, bm, bnb * 128, smem, acc);

  const int s = bnb >> 4, h = bnb & 15;
  const int t = threadIdx.x, lane = t & 63, w = t >> 6;
  const int wm = (w >> 1) * 64, wn = (w & 1) * 64;
  const int quad = lane >> 4, l16 = lane & 15;
  const int bq = bm >> 11;               // batch index (tiles never straddle batches)
  const int tpos0 = bm & (TSEQ - 1);
  unsigned short* sC = smem;             // safe: core ends with a barrier

  if (s < 2) {
    const float scl = (s == 0) ? 0.08838834764831845f : 1.0f;  // 1/sqrt(128) folded into Q
#pragma unroll
    for (int j = 0; j < 4; j++) {
      int d = wn + j * 16 + l16;
      float invf = __expf(-(float)(d >> 1) * 0.14391157f);  // ln(10000)/64
#pragma unroll
      for (int i = 0; i < 4; i++) {
#pragma unroll
        for (int r = 0; r < 4; r++) {
          int row = wm + i * 16 + quad * 4 + r;   // tile-local tpos
          float ang = (float)(tpos0 + row) * invf;
          float sn, cs;
          __sincosf(ang, &sn, &cs);
          float v = acc[i][j][r];
          float p = __shfl_xor(v, 1, 64);  // partner column d^1 (adjacent lane)
          float outv = (d & 1) ? (v * cs + p * sn) : (v * cs - p * sn);
          sC[row * 136 + d] = f2b(outv * scl);
        }
      }
    }
    __syncthreads();
    unsigned short* dst = (s == 0) ? Qd : Kd;
    size_t gbase = ((size_t)(bq * 16 + h) * TSEQ + tpos0) * 128;
#pragma unroll
    for (int it = 0; it < 8; it++) {
      int c = t + 256 * it;
      int row = c >> 4, off = (c & 15) * 8;
      uint4 vv = *(const uint4*)(sC + row * 136 + off);
      *(uint4*)(dst + gbase + (size_t)row * 128 + off) = vv;
    }
  } else {
    // V stored transposed (B,H,D,T): stage as sC[d][tpos_local], then 16B stores along T
#pragma unroll
    for (int j = 0; j < 4; j++) {
      int d = wn + j * 16 + l16;
#pragma unroll
      for (int i = 0; i < 4; i++)
#pragma unroll
        for (int r = 0; r < 4; r++) {
          int col = wm + i * 16 + quad * 4 + r;
          sC[d * 136 + col] = f2b(acc[i][j][r]);
        }
    }
    __syncthreads();
    size_t gbase = ((size_t)(bq * 16 + h) * 128) * TSEQ + tpos0;
#pragma unroll
    for (int it = 0; it < 8; it++) {
      int c = t + 256 * it;
      int row = c >> 4, off = (c & 15) * 8;   // row = d, off = tpos-local
      uint4 vv = *(const uint4*)(sC + row * 136 + off);
      *(uint4*)(Vtd + gbase + (size_t)row * TSEQ + off) = vv;
    }
  }
}

// ---------------- Flash attention v2 ----------------
// Pair-balanced causal schedule: block (pair, bh) handles q-tiles qA=pair, qB=31-pair
// (33 tile-computes per block, K/V tile at each kb loaded ONCE for both tiles).
// Double-buffered K/V in LDS (prefetch issued after the top barrier so it overlaps
// compute); XOR-swizzled 16B-chunk placement kills the 16-way bank conflicts
// (row strides 256B/128B put all 16 l16-lanes in one bank otherwise).
// LDS: 2*(8192+8192) + 4*16*72 = 74752 B -> 2 blocks/CU; VGPR capped via (256,2).
__global__ __launch_bounds__(256, 2) void attn_kernel(const unsigned short* __restrict__ Q,
                                                      const unsigned short* __restrict__ Kmat,
                                                      const unsigned short* __restrict__ Vt,
                                                      unsigned short* __restrict__ Ob) {
  __shared__ unsigned short smem[37376];
  const int pair = blockIdx.x, bh = blockIdx.y;
  const int qA = pair, qB = 31 - pair;
  const int t = threadIdx.x, lane = t & 63, w = t >> 6, quad = lane >> 4, l16 = lane & 15;
  const size_t base = (size_t)bh * TSEQ * 128;
  const unsigned short* Qp = Q + base;
  const unsigned short* Kp = Kmat + base;
  const unsigned short* Vp = Vt + base;
  unsigned short* myP = smem + 32768 + w * 1152;   // 16 x 72 per wave

  bf16x8 aqA[4], aqB[4];
  {
    int qrA = qA * 64 + w * 16 + l16;
    int qrB = qB * 64 + w * 16 + l16;
#pragma unroll
    for (int kk = 0; kk < 4; kk++) {
      aqA[kk] = *(const bf16x8*)(Qp + (size_t)qrA * 128 + kk * 32 + quad * 8);
      aqB[kk] = *(const bf16x8*)(Qp + (size_t)qrB * 128 + kk * 32 + quad * 8);
    }
  }
  const f32x4 z = {0.f, 0.f, 0.f, 0.f};
  f32x4 oA[8], oB[8];
  float mA[4], lA[4], mB[4], lB[4];
#pragma unroll
  for (int dt = 0; dt < 8; dt++) { oA[dt] = z; oB[dt] = z; }
#pragma unroll
  for (int r = 0; r < 4; r++) { mA[r] = -1e30f; lA[r] = 0.f; mB[r] = -1e30f; lB[r] = 0.f; }

  // swizzled K/V tile load: chunk c of row r lives at slot (c ^ (r&7))
  auto load_tiles = [&](int kb, int buf) {
    unsigned short* bK = smem + buf * 16384;
    unsigned short* bV = bK + 8192;
    const unsigned short* Kt = Kp + (size_t)kb * 64 * 128;
#pragma unroll
    for (int i2 = 0; i2 < 4; i2++) {
      int idx = t + 256 * i2;                       // LDS linear 16B-chunk
      int r = idx >> 4, cS = idx & 15;
      int c = cS ^ (r & 7);
      gload_lds16(Kt + r * 128 + c * 8, bK + idx * 8);
    }
#pragma unroll
    for (int i2 = 0; i2 < 4; i2++) {
      int idx = t + 256 * i2;
      int r = idx >> 3, cS = idx & 7;               // r = d index
      int c = cS ^ (r & 7);
      gload_lds16(Vp + (size_t)r * TSEQ + kb * 64 + c * 8, bV + idx * 8);
    }
  };

  auto process = [&](bf16x8 (&aq)[4], f32x4 (&o)[8], float (&mst)[4], float (&lst)[4],
                     int qb, int kb, const unsigned short* bK, const unsigned short* bV) {
    f32x4 S[4];
#pragma unroll
    for (int nt = 0; nt < 4; nt++) {
      f32x4 sacc = z;
#pragma unroll
      for (int kk = 0; kk < 4; kk++) {
        const unsigned short* p =
            bK + (nt * 16 + l16) * 128 + (((kk * 4 + quad) ^ (l16 & 7)) * 8);
        sacc = mfma16(aq[kk], *(const bf16x8*)p, sacc);
      }
      S[nt] = sacc;
    }
    if (kb == qb) {  // diagonal tile: mask key > q
      int qg = qb * 64 + w * 16 + quad * 4;
#pragma unroll
      for (int nt = 0; nt < 4; nt++) {
        int key = kb * 64 + nt * 16 + l16;
#pragma unroll
        for (int r = 0; r < 4; r++)
          if (key > qg + r) S[nt][r] = -1e30f;
      }
    }
    float alpha[4];
#pragma unroll
    for (int r = 0; r < 4; r++) {
      float mx = fmaxf(fmaxf(S[0][r], S[1][r]), fmaxf(S[2][r], S[3][r]));
      mx = fmaxf(mx, __shfl_xor(mx, 1, 64));
      mx = fmaxf(mx, __shfl_xor(mx, 2, 64));
      mx = fmaxf(mx, __shfl_xor(mx, 4, 64));
      mx = fmaxf(mx, __shfl_xor(mx, 8, 64));
      float mnew = fmaxf(mst[r], mx);
      alpha[r] = __expf(mst[r] - mnew);
      mst[r] = mnew;
    }
    float rs[4] = {0.f, 0.f, 0.f, 0.f};
#pragma unroll
    for (int nt = 0; nt < 4; nt++)
#pragma unroll
      for (int r = 0; r < 4; r++) {
        float p = __expf(S[nt][r] - mst[r]);
        S[nt][r] = p;
        rs[r] += p;
      }
#pragma unroll
    for (int r = 0; r < 4; r++) {
      float s4 = rs[r];
      s4 += __shfl_xor(s4, 1, 64);
      s4 += __shfl_xor(s4, 2, 64);
      s4 += __shfl_xor(s4, 4, 64);
      s4 += __shfl_xor(s4, 8, 64);
      lst[r] = lst[r] * alpha[r] + s4;
#pragma unroll
      for (int nt = 0; nt < 4; nt++)
        myP[(quad * 4 + r) * 72 + nt * 16 + l16] = f2b(S[nt][r]);
    }
#pragma unroll
    for (int dt = 0; dt < 8; dt++) {
      f32x4 ov = o[dt];
      ov[0] *= alpha[0]; ov[1] *= alpha[1]; ov[2] *= alpha[2]; ov[3] *= alpha[3];
      o[dt] = ov;
    }
#pragma unroll
    for (int kk = 0; kk < 2; kk++) {
      bf16x8 ap = *(const bf16x8*)(myP + l16 * 72 + kk * 32 + quad * 8);
#pragma unroll
      for (int dt = 0; dt < 8; dt++) {
        const unsigned short* p =
            bV + (dt * 16 + l16) * 64 + (((kk * 4 + quad) ^ (l16 & 7)) * 8);
        o[dt] = mfma16(ap, *(const bf16x8*)p, o[dt]);
      }
    }
  };

  load_tiles(0, 0);
#pragma unroll 1
  for (int kb = 0; kb <= qB; kb++) {
    __syncthreads();                      // drains loads for current buffer
    if (kb < qB) load_tiles(kb + 1, (kb + 1) & 1);  // prefetch overlaps compute below
    const unsigned short* bK = smem + (kb & 1) * 16384;
    const unsigned short* bV = bK + 8192;
    process(aqB, oB, mB, lB, qB, kb, bK, bV);
    if (kb <= qA) process(aqA, oA, mA, lA, qA, kb, bK, bV);
  }

  // epilogue: both tiles -> LDS (stride 136) -> coalesced 16B stores to Ob (b,t,h,d)
  __syncthreads();                        // all waves done reading K/V buffers
  unsigned short* sOA = smem;             // 64 x 136
  unsigned short* sOB = smem + 8704;      // 64 x 136
#pragma unroll
  for (int dt = 0; dt < 8; dt++)
#pragma unroll
    for (int r = 0; r < 4; r++) {
      int row = w * 16 + quad * 4 + r;
      sOA[row * 136 + dt * 16 + l16] = f2b(oA[dt][r] / lA[r]);
      sOB[row * 136 + dt * 16 + l16] = f2b(oB[dt][r] / lB[r]);
    }
  __syncthreads();
  const int b = bh >> 4, h = bh & 15;
#pragma unroll
  for (int it = 0; it < 4; it++) {
    int c = t + 256 * it;
    int row = c >> 4, off = (c & 15) * 8;
    uint4 va = *(const uint4*)(sOA + row * 136 + off);
    *(uint4*)(Ob + (size_t)(b * TSEQ + qA * 64 + row) * 2048 + h * 128 + off) = va;
    uint4 vb = *(const uint4*)(sOB + row * 136 + off);
    *(uint4*)(Ob + (size_t)(b * TSEQ + qB * 64 + row) * 2048 + h * 128 + off) = vb;
  }
}

// ---------------- GEMM2: out = Ob @ W_out, fp32 epilogue ----------------
__global__ __launch_bounds__(256, 4) void gemm_out_kernel(const unsigned short* __restrict__ Ob,
                                                          const unsigned short* __restrict__ Wot,
                                                          float* __restrict__ Cout) {
  __shared__ unsigned short smem[16384];  // dbuf core
  f32x4 acc[4][4];
  const f32x4 z = {0.f, 0.f, 0.f, 0.f};
#pragma unroll
  for (int i = 0; i < 4; i++)
#pragma unroll
    for (int j = 0; j < 4; j++) acc[i][j] = z;

  const int bm = blockIdx.y * 128, bn = blockIdx.x * 128;
  gemm_bt_core_db(Ob, Wot, 2048, bm, bn, smem, acc);

  const int t = threadIdx.x, lane = t & 63, w = t >> 6;
  const int wm = (w >> 1) * 64, wn = (w & 1) * 64;
  const int quad = lane >> 4, l16 = lane & 15;
#pragma unroll
  for (int i = 0; i < 4; i++)
#pragma unroll
    for (int j = 0; j < 4; j++)
#pragma unroll
      for (int r = 0; r < 4; r++) {
        int row = bm + wm + i * 16 + quad * 4 + r;
        int col = bn + wn + j * 16 + l16;
        Cout[(size_t)row * 2048 + col] = acc[i][j][r];
      }
}

// ---------------- launch ----------------
extern "C" void kernel_launch(void* const* d_in, const int* in_sizes, int n_in,
                              void* d_out, int out_size, void* d_ws, size_t ws_size,
                              hipStream_t stream) {
  (void)in_sizes; (void)n_in; (void)out_size; (void)ws_size;
  const float* x = (const float*)d_in[0];       // (2,2048,2048)
  const float* Wqkv = (const float*)d_in[1];    // (2048,6144)
  const float* Wout = (const float*)d_in[2];    // (2048,2048)
  float* out = (float*)d_out;                   // (2,2048,2048) fp32
  char* ws = (char*)d_ws;

  unsigned short* Xb  = (unsigned short*)(ws);               // 16 MB  (4096x2048 bf16)
  unsigned short* Wqt = (unsigned short*)(ws + 16777216);    // 24 MB  (6144x2048 bf16, W_qkv^T)
  unsigned short* Wot = (unsigned short*)(ws + 41943040);    // 8 MB   (2048x2048 bf16, W_out^T)
  unsigned short* Qd  = (unsigned short*)(ws + 50331648);    // 16 MB  (B,H,T,D)
  unsigned short* Kd  = (unsigned short*)(ws + 67108864);    // 16 MB  (B,H,T,D)
  unsigned short* Vtd = (unsigned short*)(ws + 83886080);    // 16 MB  (B,H,D,T)
  unsigned short* Obf = (unsigned short*)(ws + 100663296);   // 16 MB  (4096x2048 bf16)

  cast_bf16_kernel<<<8192, 256, 0, stream>>>(x, Xb);
  transpose_cast_kernel<<<dim3(96, 32), 256, 0, stream>>>(Wqkv, Wqt, 2048, 6144);
  transpose_cast_kernel<<<dim3(32, 32), 256, 0, stream>>>(Wout, Wot, 2048, 2048);
  gemm_qkv_rope<<<dim3(48, 32), 256, 0, stream>>>(Xb, Wqt, Qd, Kd, Vtd);
  attn_kernel<<<dim3(16, 32), 256, 0, stream>>>(Qd, Kd, Vtd, Obf);
  gemm_out_kernel<<<dim3(16, 32), 256, 0, stream>>>(Obf, Wot, out);
}

// Round 5
// 384.336 us; speedup vs baseline: 6.5390x; 1.0501x over previous
//
#include <hip/hip_runtime.h>
#include <stdint.h>

// Problem constants: B=2, T=2048, C=2048, H=16, D=128
#define TSEQ 2048

typedef __bf16 bf16x8 __attribute__((ext_vector_type(8)));
typedef float f32x4 __attribute__((ext_vector_type(4)));

typedef const __attribute__((address_space(1))) unsigned int* gas_u32;
typedef __attribute__((address_space(3))) unsigned int* las_u32;

__device__ __forceinline__ f32x4 mfma16(bf16x8 a, bf16x8 b, f32x4 c) {
  return __builtin_amdgcn_mfma_f32_16x16x32_bf16(a, b, c, 0, 0, 0);
}

// fp32 -> bf16 round-to-nearest-even (values are finite; no NaN path needed)
__device__ __forceinline__ unsigned short f2b(float f) {
  unsigned int u = __float_as_uint(f);
  u += 0x7fffu + ((u >> 16) & 1u);
  return (unsigned short)(u >> 16);
}

// async global->LDS, 16B per lane. LDS dest must be wave-uniform base + lane*16.
__device__ __forceinline__ void gload_lds16(const unsigned short* g, unsigned short* l) {
  __builtin_amdgcn_global_load_lds((gas_u32)(const void*)g, (las_u32)(void*)l, 16, 0, 0);
}

// ---------------- cast fp32 -> bf16 (vectorized, exact-size grid) ----------------
__global__ __launch_bounds__(256) void cast_bf16_kernel(const float* __restrict__ src,
                                                        unsigned short* __restrict__ dst) {
  size_t i = ((size_t)blockIdx.x * 256 + threadIdx.x) * 4;
  float4 v = *(const float4*)(src + i);
  ushort4 o;
  o.x = f2b(v.x); o.y = f2b(v.y); o.z = f2b(v.z); o.w = f2b(v.w);
  *(ushort4*)(dst + i) = o;
}

// ---------------- cast + transpose: src (R x Cc) fp32 -> dst (Cc x R) bf16 ----------------
__global__ __launch_bounds__(256) void transpose_cast_kernel(const float* __restrict__ src,
                                                             unsigned short* __restrict__ dst,
                                                             int R, int Cc) {
  __shared__ float tile[64][65];
  int cb = blockIdx.x * 64;
  int rb = blockIdx.y * 64;
  int t = threadIdx.x;
  int tr = t >> 4;          // 0..15
  int tc = (t & 15) * 4;    // 0..60
#pragma unroll
  for (int i = 0; i < 4; i++) {
    int r = tr + 16 * i;
    float4 v = *(const float4*)(src + (size_t)(rb + r) * Cc + cb + tc);
    tile[r][tc + 0] = v.x; tile[r][tc + 1] = v.y;
    tile[r][tc + 2] = v.z; tile[r][tc + 3] = v.w;
  }
  __syncthreads();
#pragma unroll
  for (int i = 0; i < 4; i++) {
    int r2 = tr + 16 * i;   // dst row = src col
    ushort4 o;
    o.x = f2b(tile[tc + 0][r2]);
    o.y = f2b(tile[tc + 1][r2]);
    o.z = f2b(tile[tc + 2][r2]);
    o.w = f2b(tile[tc + 3][r2]);
    *(ushort4*)(dst + (size_t)(cb + r2) * R + rb + tc) = o;
  }
}

// ---------------- shared GEMM main loop (double-buffered, swizzled): ----------------
// C(128x128) = A * Bt^T. m97 structure + dbuf + XOR bank-swizzle.
// Swizzle: logical 16B chunk q of row r lives at LDS slot q ^ ((r>>1)&3). Staging picks
// which GLOBAL chunk each lane fetches (LDS dests stay linear, as global_load_lds
// requires); reads land 2 lanes per 16B slot-position per 128B window -> 2-way = free
// (m136). Unswizzled, row stride 64B put all 16 l16-lanes in 2 bank groups (8-way).
// One barrier per K-step; prefetch for k+1 issued right after the barrier.
// sm layout: buf b at sm + b*8192 shorts. Trailing barrier: callers may reuse sm.
__device__ __forceinline__ void gemm_bt_core_db(const unsigned short* __restrict__ A,
                                                const unsigned short* __restrict__ Bt,
                                                int K, int bm, int bn,
                                                unsigned short* sm,
                                                f32x4 (&acc)[4][4]) {
  const int t = threadIdx.x;
  const int lane = t & 63, w = t >> 6;
  const int wm = (w >> 1) * 64, wn = (w & 1) * 64;
  const int quad = lane >> 4, l16 = lane & 15;

  const int r0 = t >> 2;                               // 0..63: row within half-tile
  const int s0 = (((t & 3) ^ ((r0 >> 1) & 3)) * 8);    // swizzled global chunk for slot t&3
  const unsigned short* Arow0 = A + (size_t)(bm + r0) * K + s0;
  const unsigned short* Arow1 = Arow0 + (size_t)64 * K;   // (r0+64)>>1 & 3 == r0>>1 & 3
  const unsigned short* Brow0 = Bt + (size_t)(bn + r0) * K + s0;
  const unsigned short* Brow1 = Brow0 + (size_t)64 * K;

  auto stage = [&](int k0, int buf) {
    unsigned short* sA = sm + buf * 8192;
    unsigned short* sB = sA + 4096;
    gload_lds16(Arow0 + k0, sA + t * 8);
    gload_lds16(Arow1 + k0, sA + (t + 256) * 8);
    gload_lds16(Brow0 + k0, sB + t * 8);
    gload_lds16(Brow1 + k0, sB + (t + 256) * 8);
  };

  const int sw = (l16 >> 1) & 3;   // (row>>1)&3 for row = wm + i*16 + l16
  stage(0, 0);
  const int nIter = K >> 5;
#pragma unroll 1
  for (int it = 0; it < nIter; it++) {
    __syncthreads();                       // drains loads for buffer it&1
    if (it + 1 < nIter) stage((it + 1) * 32, (it + 1) & 1);  // overlaps compute below
    const unsigned short* sA = sm + (it & 1) * 8192;
    const unsigned short* sB = sA + 4096;
    bf16x8 a[4], b[4];
#pragma unroll
    for (int i = 0; i < 4; i++)
      a[i] = *(const bf16x8*)(sA + (wm + i * 16 + l16) * 32 + ((quad ^ sw) * 8));
#pragma unroll
    for (int j = 0; j < 4; j++)
      b[j] = *(const bf16x8*)(sB + (wn + j * 16 + l16) * 32 + ((quad ^ sw) * 8));
#pragma unroll
    for (int i = 0; i < 4; i++)
#pragma unroll
      for (int j = 0; j < 4; j++)
        acc[i][j] = mfma16(a[i], b[j], acc[i][j]);
  }
  __syncthreads();                         // callers reuse sm right after
}

// ---------------- GEMM1: qkv = Xb @ Wqkv, fused RoPE epilogue ----------------
// blockIdx.x in [0,48): 128 cols = exactly one (s,h) head chunk. s=0:Q(+scale), 1:K, 2:V(->V^T).
// Epilogue stages the 128x128 bf16 tile in LDS (stride 136 shorts) then writes out with
// coalesced 16B/lane stores (2-byte scattered stores caused ~6.3 GB of HBM write RMW).
// LDS deliberately padded to 48 KB -> exactly 3 blocks/CU: grid is 1536 blocks, and
// 1536/768 = 2.0 full scheduling rounds (at 4 blocks/CU it was 1.5 rounds, second
// round half-idle -> ~25% makespan loss).
__global__ __launch_bounds__(256, 3) void gemm_qkv_rope(const unsigned short* __restrict__ Xb,
                                                        const unsigned short* __restrict__ Wqt,
                                                        unsigned short* __restrict__ Qd,
                                                        unsigned short* __restrict__ Kd,
                                                        unsigned short* __restrict__ Vtd) {
  __shared__ unsigned short smem[24576];  // 48 KB: core dbuf 16384 | epilogue 17408 | pad
  f32x4 acc[4][4];
  const f32x4 z = {0.f, 0.f, 0.f, 0.f};
#pragma unroll
  for (int i = 0; i < 4; i++)
#pragma unroll
    for (int j = 0; j < 4; j++) acc[i][j] = z;

  const int bm = blockIdx.y * 128;
  const int bnb = blockIdx.x;
  gemm_bt_core_db(Xb, Wqt, 2048, bm, bnb * 128, smem, acc);

  const int s = bnb >> 4, h = bnb & 15;
  const int t = threadIdx.x, lane = t & 63, w = t >> 6;
  const int wm = (w >> 1) * 64, wn = (w & 1) * 64;
  const int quad = lane >> 4, l16 = lane & 15;
  const int bq = bm >> 11;               // batch index (tiles never straddle batches)
  const int tpos0 = bm & (TSEQ - 1);
  unsigned short* sC = smem;             // safe: core ends with a barrier

  if (s < 2) {
    const float scl = (s == 0) ? 0.08838834764831845f : 1.0f;  // 1/sqrt(128) folded into Q
#pragma unroll
    for (int j = 0; j < 4; j++) {
      int d = wn + j * 16 + l16;
      float invf = __expf(-(float)(d >> 1) * 0.14391157f);  // ln(10000)/64
#pragma unroll
      for (int i = 0; i < 4; i++) {
#pragma unroll
        for (int r = 0; r < 4; r++) {
          int row = wm + i * 16 + quad * 4 + r;   // tile-local tpos
          float ang = (float)(tpos0 + row) * invf;
          float sn, cs;
          __sincosf(ang, &sn, &cs);
          float v = acc[i][j][r];
          float p = __shfl_xor(v, 1, 64);  // partner column d^1 (adjacent lane)
          float outv = (d & 1) ? (v * cs + p * sn) : (v * cs - p * sn);
          sC[row * 136 + d] = f2b(outv * scl);
        }
      }
    }
    __syncthreads();
    unsigned short* dst = (s == 0) ? Qd : Kd;
    size_t gbase = ((size_t)(bq * 16 + h) * TSEQ + tpos0) * 128;
#pragma unroll
    for (int it = 0; it < 8; it++) {
      int c = t + 256 * it;
      int row = c >> 4, off = (c & 15) * 8;
      uint4 vv = *(const uint4*)(sC + row * 136 + off);
      *(uint4*)(dst + gbase + (size_t)row * 128 + off) = vv;
    }
  } else {
    // V stored transposed (B,H,D,T): stage as sC[d][tpos_local], then 16B stores along T
#pragma unroll
    for (int j = 0; j < 4; j++) {
      int d = wn + j * 16 + l16;
#pragma unroll
      for (int i = 0; i < 4; i++)
#pragma unroll
        for (int r = 0; r < 4; r++) {
          int col = wm + i * 16 + quad * 4 + r;
          sC[d * 136 + col] = f2b(acc[i][j][r]);
        }
    }
    __syncthreads();
    size_t gbase = ((size_t)(bq * 16 + h) * 128) * TSEQ + tpos0;
#pragma unroll
    for (int it = 0; it < 8; it++) {
      int c = t + 256 * it;
      int row = c >> 4, off = (c & 15) * 8;   // row = d, off = tpos-local
      uint4 vv = *(const uint4*)(sC + row * 136 + off);
      *(uint4*)(Vtd + gbase + (size_t)row * TSEQ + off) = vv;
    }
  }
}

// ---------------- Flash attention v2 ----------------
// Pair-balanced causal schedule: block (pair, bh) handles q-tiles qA=pair, qB=31-pair
// (33 tile-computes per block, K/V tile at each kb loaded ONCE for both tiles).
// Double-buffered K/V in LDS (prefetch issued after the top barrier so it overlaps
// compute); XOR-swizzled 16B-chunk placement kills the 16-way bank conflicts
// (row strides 256B/128B put all 16 l16-lanes in one bank otherwise).
// LDS: 2*(8192+8192) + 4*16*72 = 74752 B -> 2 blocks/CU; VGPR capped via (256,2).
__global__ __launch_bounds__(256, 2) void attn_kernel(const unsigned short* __restrict__ Q,
                                                      const unsigned short* __restrict__ Kmat,
                                                      const unsigned short* __restrict__ Vt,
                                                      unsigned short* __restrict__ Ob) {
  __shared__ unsigned short smem[37376];
  const int pair = blockIdx.x, bh = blockIdx.y;
  const int qA = pair, qB = 31 - pair;
  const int t = threadIdx.x, lane = t & 63, w = t >> 6, quad = lane >> 4, l16 = lane & 15;
  const size_t base = (size_t)bh * TSEQ * 128;
  const unsigned short* Qp = Q + base;
  const unsigned short* Kp = Kmat + base;
  const unsigned short* Vp = Vt + base;
  unsigned short* myP = smem + 32768 + w * 1152;   // 16 x 72 per wave

  bf16x8 aqA[4], aqB[4];
  {
    int qrA = qA * 64 + w * 16 + l16;
    int qrB = qB * 64 + w * 16 + l16;
#pragma unroll
    for (int kk = 0; kk < 4; kk++) {
      aqA[kk] = *(const bf16x8*)(Qp + (size_t)qrA * 128 + kk * 32 + quad * 8);
      aqB[kk] = *(const bf16x8*)(Qp + (size_t)qrB * 128 + kk * 32 + quad * 8);
    }
  }
  const f32x4 z = {0.f, 0.f, 0.f, 0.f};
  f32x4 oA[8], oB[8];
  float mA[4], lA[4], mB[4], lB[4];
#pragma unroll
  for (int dt = 0; dt < 8; dt++) { oA[dt] = z; oB[dt] = z; }
#pragma unroll
  for (int r = 0; r < 4; r++) { mA[r] = -1e30f; lA[r] = 0.f; mB[r] = -1e30f; lB[r] = 0.f; }

  // swizzled K/V tile load: chunk c of row r lives at slot (c ^ (r&7))
  auto load_tiles = [&](int kb, int buf) {
    unsigned short* bK = smem + buf * 16384;
    unsigned short* bV = bK + 8192;
    const unsigned short* Kt = Kp + (size_t)kb * 64 * 128;
#pragma unroll
    for (int i2 = 0; i2 < 4; i2++) {
      int idx = t + 256 * i2;                       // LDS linear 16B-chunk
      int r = idx >> 4, cS = idx & 15;
      int c = cS ^ (r & 7);
      gload_lds16(Kt + r * 128 + c * 8, bK + idx * 8);
    }
#pragma unroll
    for (int i2 = 0; i2 < 4; i2++) {
      int idx = t + 256 * i2;
      int r = idx >> 3, cS = idx & 7;               // r = d index
      int c = cS ^ (r & 7);
      gload_lds16(Vp + (size_t)r * TSEQ + kb * 64 + c * 8, bV + idx * 8);
    }
  };

  auto process = [&](bf16x8 (&aq)[4], f32x4 (&o)[8], float (&mst)[4], float (&lst)[4],
                     int qb, int kb, const unsigned short* bK, const unsigned short* bV) {
    f32x4 S[4];
#pragma unroll
    for (int nt = 0; nt < 4; nt++) {
      f32x4 sacc = z;
#pragma unroll
      for (int kk = 0; kk < 4; kk++) {
        const unsigned short* p =
            bK + (nt * 16 + l16) * 128 + (((kk * 4 + quad) ^ (l16 & 7)) * 8);
        sacc = mfma16(aq[kk], *(const bf16x8*)p, sacc);
      }
      S[nt] = sacc;
    }
    if (kb == qb) {  // diagonal tile: mask key > q
      int qg = qb * 64 + w * 16 + quad * 4;
#pragma unroll
      for (int nt = 0; nt < 4; nt++) {
        int key = kb * 64 + nt * 16 + l16;
#pragma unroll
        for (int r = 0; r < 4; r++)
          if (key > qg + r) S[nt][r] = -1e30f;
      }
    }
    float alpha[4];
#pragma unroll
    for (int r = 0; r < 4; r++) {
      float mx = fmaxf(fmaxf(S[0][r], S[1][r]), fmaxf(S[2][r], S[3][r]));
      mx = fmaxf(mx, __shfl_xor(mx, 1, 64));
      mx = fmaxf(mx, __shfl_xor(mx, 2, 64));
      mx = fmaxf(mx, __shfl_xor(mx, 4, 64));
      mx = fmaxf(mx, __shfl_xor(mx, 8, 64));
      float mnew = fmaxf(mst[r], mx);
      alpha[r] = __expf(mst[r] - mnew);
      mst[r] = mnew;
    }
    float rs[4] = {0.f, 0.f, 0.f, 0.f};
#pragma unroll
    for (int nt = 0; nt < 4; nt++)
#pragma unroll
      for (int r = 0; r < 4; r++) {
        float p = __expf(S[nt][r] - mst[r]);
        S[nt][r] = p;
        rs[r] += p;
      }
#pragma unroll
    for (int r = 0; r < 4; r++) {
      float s4 = rs[r];
      s4 += __shfl_xor(s4, 1, 64);
      s4 += __shfl_xor(s4, 2, 64);
      s4 += __shfl_xor(s4, 4, 64);
      s4 += __shfl_xor(s4, 8, 64);
      lst[r] = lst[r] * alpha[r] + s4;
#pragma unroll
      for (int nt = 0; nt < 4; nt++)
        myP[(quad * 4 + r) * 72 + nt * 16 + l16] = f2b(S[nt][r]);
    }
#pragma unroll
    for (int dt = 0; dt < 8; dt++) {
      f32x4 ov = o[dt];
      ov[0] *= alpha[0]; ov[1] *= alpha[1]; ov[2] *= alpha[2]; ov[3] *= alpha[3];
      o[dt] = ov;
    }
#pragma unroll
    for (int kk = 0; kk < 2; kk++) {
      bf16x8 ap = *(const bf16x8*)(myP + l16 * 72 + kk * 32 + quad * 8);
#pragma unroll
      for (int dt = 0; dt < 8; dt++) {
        const unsigned short* p =
            bV + (dt * 16 + l16) * 64 + (((kk * 4 + quad) ^ (l16 & 7)) * 8);
        o[dt] = mfma16(ap, *(const bf16x8*)p, o[dt]);
      }
    }
  };

  load_tiles(0, 0);
#pragma unroll 1
  for (int kb = 0; kb <= qB; kb++) {
    __syncthreads();                      // drains loads for current buffer
    if (kb < qB) load_tiles(kb + 1, (kb + 1) & 1);  // prefetch overlaps compute below
    const unsigned short* bK = smem + (kb & 1) * 16384;
    const unsigned short* bV = bK + 8192;
    process(aqB, oB, mB, lB, qB, kb, bK, bV);
    if (kb <= qA) process(aqA, oA, mA, lA, qA, kb, bK, bV);
  }

  // epilogue: both tiles -> LDS (stride 136) -> coalesced 16B stores to Ob (b,t,h,d)
  __syncthreads();                        // all waves done reading K/V buffers
  unsigned short* sOA = smem;             // 64 x 136
  unsigned short* sOB = smem + 8704;      // 64 x 136
#pragma unroll
  for (int dt = 0; dt < 8; dt++)
#pragma unroll
    for (int r = 0; r < 4; r++) {
      int row = w * 16 + quad * 4 + r;
      sOA[row * 136 + dt * 16 + l16] = f2b(oA[dt][r] / lA[r]);
      sOB[row * 136 + dt * 16 + l16] = f2b(oB[dt][r] / lB[r]);
    }
  __syncthreads();
  const int b = bh >> 4, h = bh & 15;
#pragma unroll
  for (int it = 0; it < 4; it++) {
    int c = t + 256 * it;
    int row = c >> 4, off = (c & 15) * 8;
    uint4 va = *(const uint4*)(sOA + row * 136 + off);
    *(uint4*)(Ob + (size_t)(b * TSEQ + qA * 64 + row) * 2048 + h * 128 + off) = va;
    uint4 vb = *(const uint4*)(sOB + row * 136 + off);
    *(uint4*)(Ob + (size_t)(b * TSEQ + qB * 64 + row) * 2048 + h * 128 + off) = vb;
  }
}

// ---------------- GEMM2: out = Ob @ W_out, fp32 epilogue ----------------
__global__ __launch_bounds__(256, 4) void gemm_out_kernel(const unsigned short* __restrict__ Ob,
                                                          const unsigned short* __restrict__ Wot,
                                                          float* __restrict__ Cout) {
  __shared__ unsigned short smem[16384];  // dbuf core
  f32x4 acc[4][4];
  const f32x4 z = {0.f, 0.f, 0.f, 0.f};
#pragma unroll
  for (int i = 0; i < 4; i++)
#pragma unroll
    for (int j = 0; j < 4; j++) acc[i][j] = z;

  const int bm = blockIdx.y * 128, bn = blockIdx.x * 128;
  gemm_bt_core_db(Ob, Wot, 2048, bm, bn, smem, acc);

  const int t = threadIdx.x, lane = t & 63, w = t >> 6;
  const int wm = (w >> 1) * 64, wn = (w & 1) * 64;
  const int quad = lane >> 4, l16 = lane & 15;
#pragma unroll
  for (int i = 0; i < 4; i++)
#pragma unroll
    for (int j = 0; j < 4; j++)
#pragma unroll
      for (int r = 0; r < 4; r++) {
        int row = bm + wm + i * 16 + quad * 4 + r;
        int col = bn + wn + j * 16 + l16;
        Cout[(size_t)row * 2048 + col] = acc[i][j][r];
      }
}

// ---------------- launch ----------------
extern "C" void kernel_launch(void* const* d_in, const int* in_sizes, int n_in,
                              void* d_out, int out_size, void* d_ws, size_t ws_size,
                              hipStream_t stream) {
  (void)in_sizes; (void)n_in; (void)out_size; (void)ws_size;
  const float* x = (const float*)d_in[0];       // (2,2048,2048)
  const float* Wqkv = (const float*)d_in[1];    // (2048,6144)
  const float* Wout = (const float*)d_in[2];    // (2048,2048)
  float* out = (float*)d_out;                   // (2,2048,2048) fp32
  char* ws = (char*)d_ws;

  unsigned short* Xb  = (unsigned short*)(ws);               // 16 MB  (4096x2048 bf16)
  unsigned short* Wqt = (unsigned short*)(ws + 16777216);    // 24 MB  (6144x2048 bf16, W_qkv^T)
  unsigned short* Wot = (unsigned short*)(ws + 41943040);    // 8 MB   (2048x2048 bf16, W_out^T)
  unsigned short* Qd  = (unsigned short*)(ws + 50331648);    // 16 MB  (B,H,T,D)
  unsigned short* Kd  = (unsigned short*)(ws + 67108864);    // 16 MB  (B,H,T,D)
  unsigned short* Vtd = (unsigned short*)(ws + 83886080);    // 16 MB  (B,H,D,T)
  unsigned short* Obf = (unsigned short*)(ws + 100663296);   // 16 MB  (4096x2048 bf16)

  cast_bf16_kernel<<<8192, 256, 0, stream>>>(x, Xb);
  transpose_cast_kernel<<<dim3(96, 32), 256, 0, stream>>>(Wqkv, Wqt, 2048, 6144);
  transpose_cast_kernel<<<dim3(32, 32), 256, 0, stream>>>(Wout, Wot, 2048, 2048);
  gemm_qkv_rope<<<dim3(48, 32), 256, 0, stream>>>(Xb, Wqt, Qd, Kd, Vtd);
  attn_kernel<<<dim3(16, 32), 256, 0, stream>>>(Qd, Kd, Vtd, Obf);
  gemm_out_kernel<<<dim3(16, 32), 256, 0, stream>>>(Obf, Wot, out);
}